// Round 15
// baseline (423.928 us; speedup 1.0000x reference)
//
#include <hip/hip_runtime.h>
#include <math.h>

#define DI __device__ __forceinline__

constexpr int B_ = 8, C_ = 64, H_ = 62, T_ = 400, S_ = 32;
constexpr int HT   = H_ * T_;      // 24800
constexpr int CHT  = C_ * HT;      // 1587200
constexpr int NPOS = B_ * HT;      // 198400
constexpr int NTOT = B_ * CHT;     // 12697600

typedef __attribute__((ext_vector_type(8))) short short8;
typedef __attribute__((ext_vector_type(4))) float float4v;
typedef unsigned short bh;

DI float sigmoidf_(float x) { return 1.f / (1.f + expf(-x)); }
DI float gelu_(float x) { return 0.5f * x * (1.f + erff(x * 0.70710678118654752f)); }

template<int ACT> DI float act_(float v) {
  if (ACT == 1) return fmaxf(v, 0.f);
  if (ACT == 2) return sigmoidf_(v);
  return v;
}

DI bh f2b(float f) {                        // fp32 -> bf16 RNE
  unsigned int u = __float_as_uint(f);
  u += 0x7FFFu + ((u >> 16) & 1u);
  return (bh)(u >> 16);
}
DI float b2f(bh u) { return __uint_as_float(((unsigned int)u) << 16); }
DI unsigned int pk2(float a, float b) {
  return (unsigned int)f2b(a) | ((unsigned int)f2b(b) << 16);
}

// ---------- prep: weights -> bf16 A-fragment layout, bn gain folded ----------
__global__ __launch_bounds__(256) void prep(const float* __restrict__ in_w,
    const float* __restrict__ dwpw, const float* __restrict__ dwg,
    const float* __restrict__ d1pw, const float* __restrict__ d1g,
    const float* __restrict__ outw, const float* __restrict__ outg,
    bh* __restrict__ wf) {
  int idx = blockIdx.x * 256 + threadIdx.x;     // 4096 fragments
  int lane = idx & 63, kc = (idx >> 6) & 1, w = (idx >> 7) & 3, slot = idx >> 9;
  const float* src; const float* g;
  switch (slot) {
    case 0: src = in_w;            g = nullptr;      break;
    case 1: src = dwpw + 0 * 4096; g = dwg + 0 * 64; break;
    case 2: src = dwpw + 1 * 4096; g = dwg + 1 * 64; break;
    case 3: src = d1pw + 0 * 4096; g = d1g + 0 * 64; break;
    case 4: src = dwpw + 2 * 4096; g = dwg + 2 * 64; break;
    case 5: src = dwpw + 3 * 4096; g = dwg + 3 * 64; break;
    case 6: src = d1pw + 1 * 4096; g = d1g + 1 * 64; break;
    default: src = outw;           g = outg;         break;
  }
  int o = w * 16 + (lane & 15);
  float gv = g ? g[o] : 1.f;
  unsigned int pack[4];
  #pragma unroll
  for (int h = 0; h < 4; ++h) {
    int c = kc * 32 + (lane >> 4) * 8 + h * 2;
    pack[h] = pk2(src[o * 64 + c] * gv, src[o * 64 + c + 1] * gv);
  }
  *(uint4*)&wf[idx * 8] = make_uint4(pack[0], pack[1], pack[2], pack[3]);
}

// ---------- pointwise 64x64 conv via MFMA (+ optional fused SSM/LN/gate) -----
// 1550 blocks x 256 thr; 128 pos x 64 out, K=64. X staged to LDS bf16 [p][c]
// (stride 72, XOR swizzle). K8F: epilogue = SSM pointwise + residual +
// channel-LayerNorm + spatial gate, writing X_out directly (cb never stored).
template<int ACT, bool REV, bool SPAT, bool DW13, bool INF32, bool OUTF32, bool K8F>
__global__ __launch_bounds__(256) void pwk(const void* __restrict__ in_,
    const bh* __restrict__ wf, const float* __restrict__ bb,
    const float* __restrict__ ac, const float* __restrict__ w3,
    void* __restrict__ out_, float* __restrict__ comb,
    const bh* __restrict__ b2g, const float* __restrict__ asg,
    const float* __restrict__ ctg, const float* __restrict__ Dg,
    const float* __restrict__ lngg, const float* __restrict__ lnbg, int rev) {
  constexpr int XB_B = 128 * 72 * 2;                    // 18432
  constexpr int MAIN_B = K8F ? 128 * 65 * 4 : XB_B;     // ctl overlays Xb
  constexpr int RED_B = (K8F || SPAT) ? 4096 : 0;
  __shared__ __align__(16) char smr_[MAIN_B + RED_B];
  bh* Xb = (bh*)smr_;
  const int tid = threadIdx.x;
  const int lane = tid & 63;
  const int wv = tid >> 6;
  const int p0 = blockIdx.x * 128;
  // ---- stage X tile: thread = 4 positions x 8 channels
  {
    const int ps = (tid & 31) * 4;
    const int cs = (tid >> 5) * 8;
    const int p4 = p0 + ps;
    const int b = p4 / HT, ht = p4 - b * HT;
    const int row = ht / T_, t0 = ht - row * T_;
    float xv[8][4];
    if constexpr (INF32) {
      const float* rp0 = (const float*)in_ + b * CHT + row * T_;
      #pragma unroll
      for (int cj = 0; cj < 8; ++cj) {
        const float* rp = rp0 + (cs + cj) * HT;
        if constexpr (REV) {
          float4 u = *(const float4*)&rp[T_ - 4 - t0];
          xv[cj][0] = u.w; xv[cj][1] = u.z; xv[cj][2] = u.y; xv[cj][3] = u.x;
        } else {
          float4 u = *(const float4*)&rp[t0];
          xv[cj][0] = u.x; xv[cj][1] = u.y; xv[cj][2] = u.z; xv[cj][3] = u.w;
        }
      }
    } else if constexpr (DW13) {
      const bh* rp0 = (const bh*)in_ + b * CHT + row * T_;
      #pragma unroll
      for (int cj = 0; cj < 8; ++cj) {
        const int c = cs + cj;
        const bh* rp = rp0 + c * HT;
        ushort4 u = *(const ushort4*)&rp[t0];
        float x0 = b2f(u.x), x1 = b2f(u.y), x2 = b2f(u.z), x3 = b2f(u.w);
        float xm = (t0 > 0)      ? b2f(rp[t0 - 1]) : 0.f;
        float xp = (t0 < T_ - 4) ? b2f(rp[t0 + 4]) : 0.f;
        float s0 = xm * xm, s1 = x0 * x0, s2 = x1 * x1;
        float s3 = x2 * x2, s4 = x3 * x3, s5 = xp * xp;
        float acv = ac[b * 64 + c];
        float c0 = w3[c * 3 + 0] * acv, c1 = w3[c * 3 + 1] * acv,
              c2 = w3[c * 3 + 2] * acv;
        xv[cj][0] = c0 * s0 + c1 * s1 + c2 * s2;
        xv[cj][1] = c0 * s1 + c1 * s2 + c2 * s3;
        xv[cj][2] = c0 * s2 + c1 * s3 + c2 * s4;
        xv[cj][3] = c0 * s3 + c1 * s4 + c2 * s5;
      }
    } else {
      const bh* rp0 = (const bh*)in_ + b * CHT + row * T_;
      #pragma unroll
      for (int cj = 0; cj < 8; ++cj) {
        const bh* rp = rp0 + (cs + cj) * HT;
        ushort4 u;
        if constexpr (REV) {
          u = *(const ushort4*)&rp[T_ - 4 - t0];
          xv[cj][0] = b2f(u.w); xv[cj][1] = b2f(u.z);
          xv[cj][2] = b2f(u.y); xv[cj][3] = b2f(u.x);
        } else {
          u = *(const ushort4*)&rp[t0];
          xv[cj][0] = b2f(u.x); xv[cj][1] = b2f(u.y);
          xv[cj][2] = b2f(u.z); xv[cj][3] = b2f(u.w);
        }
      }
    }
    #pragma unroll
    for (int pi = 0; pi < 4; ++pi) {
      int r = ps + pi;
      int col = cs ^ (((r >> 2) & 7) << 3);       // swizzle (8-bh blocks)
      uint4 w4;
      w4.x = pk2(xv[0][pi], xv[1][pi]);
      w4.y = pk2(xv[2][pi], xv[3][pi]);
      w4.z = pk2(xv[4][pi], xv[5][pi]);
      w4.w = pk2(xv[6][pi], xv[7][pi]);
      *(uint4*)&Xb[r * 72 + col] = w4;
    }
  }
  // ---- A fragments (weights), coalesced 16B per lane
  short8 af0 = *(const short8*)(wf + ((wv * 2 + 0) * 64 + lane) * 8);
  short8 af1 = *(const short8*)(wf + ((wv * 2 + 1) * 64 + lane) * 8);
  const int m4 = (lane >> 4) * 4;
  float binit[4];
  #pragma unroll
  for (int j = 0; j < 4; ++j) binit[j] = bb ? bb[wv * 16 + m4 + j] : 0.f;
  __syncthreads();
  // ---- MFMA: 8 M-tiles (position groups) x 2 K-chunks
  float4v acc[8];
  #pragma unroll
  for (int nt = 0; nt < 8; ++nt) { acc[nt][0] = acc[nt][1] = acc[nt][2] = acc[nt][3] = 0.f; }
  #pragma unroll
  for (int nt = 0; nt < 8; ++nt) {
    int r = nt * 16 + (lane & 15);
    int sw = ((r >> 2) & 7) << 3;
    int cb0 = ((lane >> 4) * 8) ^ sw;
    int cb1 = (32 + (lane >> 4) * 8) ^ sw;
    short8 b0 = *(const short8*)&Xb[r * 72 + cb0];
    short8 b1 = *(const short8*)&Xb[r * 72 + cb1];
    acc[nt] = __builtin_amdgcn_mfma_f32_16x16x32_bf16(af0, b0, acc[nt], 0, 0, 0);
    acc[nt] = __builtin_amdgcn_mfma_f32_16x16x32_bf16(af1, b1, acc[nt], 0, 0, 0);
  }
  if constexpr (K8F) {
    // ================= fused SSM + LN + spatial gate epilogue ==============
    __syncthreads();                         // all Xb reads complete
    float* ctl  = (float*)smr_;              // [128][65], overlays Xb
    float* redA = (float*)(smr_ + MAIN_B);   // [4][128]
    float* redB = redA + 512;                // [4][128]
    for (int e = tid; e < 128 * 64; e += 256) {
      int r = e >> 6, c2 = e & 63;
      int p = p0 + r;
      int ht = p % HT;
      int t = ht % T_;
      ctl[r * 65 + c2] = ctg[t * 64 + c2];
    }
    __syncthreads();
    int offs[8], wof[8], h8[8];
    float av8[8];
    #pragma unroll
    for (int nt = 0; nt < 8; ++nt) {
      int p = p0 + nt * 16 + (lane & 15);
      int b = p / HT, ht = p - b * HT;
      int h = ht / T_, t = ht - h * T_;
      offs[nt] = b * CHT + ht;
      wof[nt] = b * CHT + (rev ? (h * T_ + T_ - 1 - t) : ht);
      h8[nt] = h;
      av8[nt] = asg[p];
    }
    // v = cb + gelu(ct + cb*D), in place over acc
    #pragma unroll
    for (int nt = 0; nt < 8; ++nt) {
      int r = nt * 16 + (lane & 15);
      #pragma unroll
      for (int j = 0; j < 4; ++j) {
        int c = wv * 16 + m4 + j;
        float cbv = act_<ACT>(acc[nt][j] + binit[j]);
        int c2 = (h8[nt] - 2 * c) & 63;      // (62c+h) mod 64
        float u = ctl[r * 65 + c2] + cbv * Dg[c2];
        acc[nt][j] = cbv + gelu_(u);
      }
    }
    // LN pass 1: mean over channels
    #pragma unroll
    for (int nt = 0; nt < 8; ++nt) {
      float s = acc[nt][0] + acc[nt][1] + acc[nt][2] + acc[nt][3];
      s += __shfl_xor(s, 16); s += __shfl_xor(s, 32);
      if (lane < 16) redA[wv * 128 + nt * 16 + lane] = s;
    }
    __syncthreads();
    float mu8[8];
    #pragma unroll
    for (int nt = 0; nt < 8; ++nt) {
      int q = nt * 16 + (lane & 15);
      mu8[nt] = (redA[q] + redA[128 + q] + redA[256 + q] + redA[384 + q])
                * (1.f / 64.f);
    }
    // LN pass 2: variance
    #pragma unroll
    for (int nt = 0; nt < 8; ++nt) {
      float d0 = acc[nt][0] - mu8[nt], d1 = acc[nt][1] - mu8[nt];
      float d2 = acc[nt][2] - mu8[nt], d3 = acc[nt][3] - mu8[nt];
      float qv = d0 * d0 + d1 * d1 + d2 * d2 + d3 * d3;
      qv += __shfl_xor(qv, 16); qv += __shfl_xor(qv, 32);
      if (lane < 16) redB[wv * 128 + nt * 16 + lane] = qv;
    }
    __syncthreads();
    float rstd8[8];
    #pragma unroll
    for (int nt = 0; nt < 8; ++nt) {
      int q = nt * 16 + (lane & 15);
      float Q = redB[q] + redB[128 + q] + redB[256 + q] + redB[384 + q];
      rstd8[nt] = rsqrtf(Q * (1.f / 64.f) + 1e-5f);
    }
    // gate + store
    #pragma unroll
    for (int nt = 0; nt < 8; ++nt) {
      #pragma unroll
      for (int j = 0; j < 4; ++j) {
        int c = wv * 16 + m4 + j;
        float y = (acc[nt][j] - mu8[nt]) * rstd8[nt] * lngg[c] + lnbg[c];
        float bv = b2f(b2g[offs[nt] + c * HT]);
        float rr = y * sigmoidf_(bv * bv * av8[nt]);
        if constexpr (OUTF32) ((float*)out_)[wof[nt] + c * HT] = rr;
        else                  ((bh*)out_)[wof[nt] + c * HT] = f2b(rr);
      }
    }
  } else {
    // ================= plain epilogue ======================================
    float psum[8], pmaxv[8];
    #pragma unroll
    for (int nt = 0; nt < 8; ++nt) {
      int n = nt * 16 + (lane & 15);
      int p = p0 + n;
      int b = p / HT, ht = p - b * HT;
      float s = 0.f, m = -3.4e38f;
      if constexpr (OUTF32) {
        float* op = (float*)out_ + b * CHT + ht + (wv * 16 + m4) * HT;
        #pragma unroll
        for (int j = 0; j < 4; ++j) {
          float r = act_<ACT>(acc[nt][j] + binit[j]);
          op[j * HT] = r;
          if constexpr (SPAT) { s += r; m = fmaxf(m, r); }
        }
      } else {
        bh* op = (bh*)out_ + b * CHT + ht + (wv * 16 + m4) * HT;
        #pragma unroll
        for (int j = 0; j < 4; ++j) {
          float r = act_<ACT>(acc[nt][j] + binit[j]);
          op[j * HT] = f2b(r);
          if constexpr (SPAT) { s += r; m = fmaxf(m, r); }
        }
      }
      if constexpr (SPAT) {
        s += __shfl_xor(s, 16); s += __shfl_xor(s, 32);
        m = fmaxf(m, __shfl_xor(m, 16)); m = fmaxf(m, __shfl_xor(m, 32));
        psum[nt] = s; pmaxv[nt] = m;
      }
    }
    if constexpr (SPAT) {
      float* redS = (float*)(smr_ + MAIN_B);   // [4][128]
      float* redM = redS + 512;
      if (lane < 16) {
        #pragma unroll
        for (int nt = 0; nt < 8; ++nt) {
          redS[wv * 128 + nt * 16 + lane] = psum[nt];
          redM[wv * 128 + nt * 16 + lane] = pmaxv[nt];
        }
      }
      __syncthreads();
      if (tid < 128) {
        float s = redS[tid] + redS[128 + tid] + redS[256 + tid] + redS[384 + tid];
        float m = fmaxf(fmaxf(redM[tid], redM[128 + tid]),
                        fmaxf(redM[256 + tid], redM[384 + tid]));
        int pp = p0 + tid;
        int b2i = pp / HT, ht2 = pp - b2i * HT;
        comb[b2i * 2 * HT + ht2] = s * (1.f / 64.f);
        comb[b2i * 2 * HT + HT + ht2] = m;
      }
    }
  }
}

// ---------- dual 5x5 depthwise conv, pad 2: f32 in, bf16 out ----------
__global__ __launch_bounds__(256) void dw5dual(const float* __restrict__ in,
    const float* __restrict__ w0_, const float* __restrict__ w1_,
    bh* __restrict__ out0, bh* __restrict__ out1) {
  const int bc = blockIdx.y;
  const int c = bc & 63;
  int task = blockIdx.x * 256 + threadIdx.x;
  if (task >= 62 * 25) return;             // 62 rows * 25 chunks of 16
  int h = task / 25;
  int t0 = (task - h * 25) << 4;
  const float* base = in + (size_t)bc * HT;
  const float* wp0 = w0_ + c * 25;
  const float* wp1 = w1_ + c * 25;
  float acc0[16], acc1[16];
  #pragma unroll
  for (int j = 0; j < 16; ++j) { acc0[j] = 0.f; acc1[j] = 0.f; }
  const bool fast = (t0 >= 4) && (t0 <= 380);
  #pragma unroll 1
  for (int u = 0; u < 5; ++u) {
    int hh = h + u - 2;
    if (hh < 0 || hh >= H_) continue;
    const float* row = base + hh * T_;
    float win[24];
    if (fast) {
      #pragma unroll
      for (int j = 0; j < 6; ++j)
        *(float4*)&win[4 * j] = *(const float4*)&row[t0 - 4 + 4 * j];
    } else {
      #pragma unroll
      for (int k = 0; k < 24; ++k) {
        int tt = t0 - 4 + k;
        win[k] = (tt >= 0 && tt < T_) ? row[tt] : 0.f;
      }
    }
    #pragma unroll
    for (int v = 0; v < 5; ++v) {
      float wa = wp0[u * 5 + v];            // uniform -> SGPR
      float wb = wp1[u * 5 + v];
      #pragma unroll
      for (int j = 0; j < 16; ++j) {
        float x = win[j + v + 2];
        acc0[j] += wa * x;
        acc1[j] += wb * x;
      }
    }
  }
  unsigned int pk0[8], pk1[8];
  #pragma unroll
  for (int j = 0; j < 8; ++j) {
    pk0[j] = pk2(acc0[2 * j], acc0[2 * j + 1]);
    pk1[j] = pk2(acc1[2 * j], acc1[2 * j + 1]);
  }
  bh* o0 = out0 + (size_t)bc * HT + h * T_ + t0;
  bh* o1 = out1 + (size_t)bc * HT + h * T_ + t0;
  *(uint4*)&o0[0] = make_uint4(pk0[0], pk0[1], pk0[2], pk0[3]);
  *(uint4*)&o0[8] = make_uint4(pk0[4], pk0[5], pk0[6], pk0[7]);
  *(uint4*)&o1[0] = make_uint4(pk1[0], pk1[1], pk1[2], pk1[3]);
  *(uint4*)&o1[8] = make_uint4(pk1[4], pk1[5], pk1[6], pk1[7]);
}

// ---------- channel attention: raw-sum+max over half a (H,T) plane (bf16) ----
__global__ __launch_bounds__(256) void chanred(const bh* __restrict__ in,
    float* __restrict__ sum_, float* __restrict__ max_) {
  int bc = blockIdx.x >> 1, hf = blockIdx.x & 1;
  const bh* base = in + (size_t)bc * HT + hf * (HT / 2);
  float s = 0.f, m = -3.4e38f;
  for (int i = threadIdx.x * 2; i < HT / 2; i += 512) {
    ushort2 q = *(const ushort2*)&base[i];
    float v0 = b2f(q.x), v1 = b2f(q.y);
    s += v0 + v1; m = fmaxf(m, fmaxf(v0, v1));
  }
  #pragma unroll
  for (int off = 32; off > 0; off >>= 1) {
    s += __shfl_down(s, off);
    m = fmaxf(m, __shfl_down(m, off));
  }
  __shared__ float ss[4], sm[4];
  int wv = threadIdx.x >> 6;
  if ((threadIdx.x & 63) == 0) { ss[wv] = s; sm[wv] = m; }
  __syncthreads();
  if (threadIdx.x == 0) {
    float S = ss[0] + ss[1] + ss[2] + ss[3];
    float M = fmaxf(fmaxf(sm[0], sm[1]), fmaxf(sm[2], sm[3]));
    sum_[hf * 512 + bc] = S;
    max_[hf * 512 + bc] = M;
  }
}

// ---------- channel attention FC: ac[b,c] = sigmoid(fc(avg)+fc(max)) ----------
__global__ __launch_bounds__(512) void cafc(const float* __restrict__ cs,
    const float* __restrict__ cm, const float* __restrict__ w1,
    const float* __restrict__ w2, float* __restrict__ ac) {
  __shared__ float sa[512], sx[512], hsum[8][4];
  int tid = threadIdx.x;
  sa[tid] = (cs[tid] + cs[512 + tid]) * (1.f / HT);
  sx[tid] = fmaxf(cm[tid], cm[512 + tid]);
  __syncthreads();
  if (tid < 32) {
    int b = tid >> 2, m = tid & 3;
    float s1 = 0.f, s2 = 0.f;
    #pragma unroll
    for (int cc = 0; cc < 64; ++cc) {
      float wv = w1[m * 64 + cc];
      s1 += sa[b * 64 + cc] * wv;
      s2 += sx[b * 64 + cc] * wv;
    }
    hsum[b][m] = fmaxf(s1, 0.f) + fmaxf(s2, 0.f);
  }
  __syncthreads();
  int b = tid >> 6, cc = tid & 63;
  float f = 0.f;
  #pragma unroll
  for (int m = 0; m < 4; ++m) f += hsum[b][m] * w2[cc * 4 + m];
  ac[tid] = sigmoidf_(f);
}

// ---------- 7x7 conv over 2 channels + sigmoid (LDS row-pair tile) ----------
__global__ __launch_bounds__(256) void conv7(const float* __restrict__ comb,
    const float* __restrict__ w, float* __restrict__ as_) {
  __shared__ float sm[2][8][408];
  __shared__ float sw[98];
  const int b = blockIdx.x / 31, hp = blockIdx.x % 31;
  const int h0 = hp * 2;
  const float* cb0 = comb + b * 2 * HT;
  const int tid = threadIdx.x;
  if (tid < 98) sw[tid] = w[tid];
  for (int e = tid; e < 2 * 8 * 408; e += 256) {
    int ci = e / 3264, rem = e - ci * 3264;
    int r = rem / 408, tt = rem - r * 408;
    int hh = h0 - 3 + r, t = tt - 4;
    float v = 0.f;
    if (hh >= 0 && hh < H_ && t >= 0 && t < T_) v = cb0[ci * HT + hh * T_ + t];
    sm[ci][r][tt] = v;
  }
  __syncthreads();
  for (int o = tid; o < 800; o += 256) {
    int oh = o / 400, ot = o - oh * 400;
    float acc = 0.f;
    #pragma unroll
    for (int ci = 0; ci < 2; ++ci)
      #pragma unroll
      for (int u = 0; u < 7; ++u)
        #pragma unroll
        for (int v = 0; v < 7; ++v)
          acc += sw[ci * 49 + u * 7 + v] * sm[ci][oh + u][ot + v + 1];
    as_[b * HT + (h0 + oh) * T_ + ot] = sigmoidf_(acc);
  }
}

// ---------- ssmctA: build P[i]=A^(2^i), q[i]=s_(2^i) tables (per half) ----------
__global__ __launch_bounds__(1024) void ssmctA(const float* __restrict__ A_,
    const float* __restrict__ Bv_, float* __restrict__ Pg, float* __restrict__ qg) {
  const int hf = blockIdx.x;
  const float* A = A_ + hf * 1024;
  const float* Bv = Bv_ + hf * 32;
  __shared__ float Pbuf[2][32 * 33];
  __shared__ float qbuf[2][32];
  const int tid = threadIdx.x;
  float* Pc = Pbuf[0]; float* Pn = Pbuf[1];
  float* qc = qbuf[0]; float* qn = qbuf[1];
  Pc[(tid >> 5) * 33 + (tid & 31)] = A[tid];
  if (tid < 32) qc[tid] = Bv[tid];
  __syncthreads();
  for (int i = 0; i < 9; ++i) {
    Pg[(hf * 9 + i) * 1024 + tid] = Pc[(tid >> 5) * 33 + (tid & 31)];
    if (tid < 32) qg[(hf * 9 + i) * 32 + tid] = qc[tid];
    if (i == 8) break;
    const int r = tid >> 5, cc = tid & 31;
    float s0 = 0.f, s1 = 0.f, s2 = 0.f, s3 = 0.f;
    #pragma unroll
    for (int k = 0; k < 32; k += 4) {
      s0 += Pc[r * 33 + k + 0] * Pc[(k + 0) * 33 + cc];
      s1 += Pc[r * 33 + k + 1] * Pc[(k + 1) * 33 + cc];
      s2 += Pc[r * 33 + k + 2] * Pc[(k + 2) * 33 + cc];
      s3 += Pc[r * 33 + k + 3] * Pc[(k + 3) * 33 + cc];
    }
    float qv = 0.f;
    if (tid < 32) {
      float a0 = 0.f, a1 = 0.f;
      #pragma unroll
      for (int k = 0; k < 32; k += 2) {
        a0 += Pc[tid * 33 + k] * qc[k];
        a1 += Pc[tid * 33 + k + 1] * qc[k + 1];
      }
      qv = qc[tid] + a0 + a1;
    }
    Pn[r * 33 + cc] = s0 + s1 + s2 + s3;
    if (tid < 32) qn[tid] = qv;
    __syncthreads();
    float* tp = Pc; Pc = Pn; Pn = tp;
    float* tq = qc; qc = qn; qn = tq;
  }
}

// ---------- ssmctB: per-t bit-walk (32 lanes hold the state), ct = s@Cm ----------
__global__ __launch_bounds__(1024) void ssmctB(const float* __restrict__ Pg,
    const float* __restrict__ qg, const float* __restrict__ Cm_,
    float* __restrict__ ct) {
  const int hf = blockIdx.y;
  __shared__ float P[9][32][33];
  __shared__ float q[9][32];
  __shared__ float Cs[32 * 64];
  __shared__ float st[32][33];
  const int tid = threadIdx.x;
  #pragma unroll
  for (int i = 0; i < 9; ++i) {
    int rem = tid;
    P[i][rem >> 5][rem & 31] = Pg[(hf * 9 + i) * 1024 + rem];
  }
  if (tid < 9 * 32) q[tid >> 5][tid & 31] = qg[hf * 9 * 32 + tid];
  for (int e = tid; e < 2048; e += 1024) Cs[e] = Cm_[hf * 2048 + e];
  __syncthreads();
  const int grp = tid >> 5, j = tid & 31;
  const int tIdx = blockIdx.x * 32 + grp;
  const int n = tIdx + 1;
  float s = 0.f;
  #pragma unroll
  for (int i = 0; i < 9; ++i) {
    st[grp][j] = s;                        // in-wave exchange (no barrier)
    float a0 = q[i][j], a1 = 0.f;
    #pragma unroll
    for (int k = 0; k < 32; k += 2) {
      a0 += P[i][j][k] * st[grp][k];
      a1 += P[i][j][k + 1] * st[grp][k + 1];
    }
    s = ((n >> i) & 1) ? (a0 + a1) : s;
  }
  st[grp][j] = s;
  __syncthreads();
  #pragma unroll
  for (int e0 = 0; e0 < 2048; e0 += 1024) {
    int e = e0 + tid;
    int ts = e >> 6, c = e & 63;
    float a0 = 0.f, a1 = 0.f;
    #pragma unroll
    for (int k = 0; k < 32; k += 2) {
      a0 += st[ts][k] * Cs[k * 64 + c];
      a1 += st[ts][k + 1] * Cs[(k + 1) * 64 + c];
    }
    int tg = blockIdx.x * 32 + ts;
    if (tg < T_) ct[(hf * T_ + tg) * 64 + c] = a0 + a1;
  }
}

extern "C" void kernel_launch(void* const* d_in, const int* in_sizes, int n_in,
                              void* d_out, int out_size, void* d_ws, size_t ws_size,
                              hipStream_t stream) {
  const float* x    = (const float*)d_in[0];
  const float* in_w = (const float*)d_in[1];
  const float* dwdw = (const float*)d_in[2];
  const float* dwpw = (const float*)d_in[3];
  const float* dwg  = (const float*)d_in[4];
  const float* dwb  = (const float*)d_in[5];
  const float* caw1 = (const float*)d_in[6];
  const float* caw2 = (const float*)d_in[7];
  const float* saw  = (const float*)d_in[8];
  const float* d1dw = (const float*)d_in[9];
  const float* d1pw = (const float*)d_in[10];
  const float* d1g  = (const float*)d_in[11];
  const float* d1b  = (const float*)d_in[12];
  const float* ssmA = (const float*)d_in[13];
  const float* ssmBv= (const float*)d_in[14];
  const float* ssmC = (const float*)d_in[15];
  const float* ssmD = (const float*)d_in[16];
  const float* lng  = (const float*)d_in[17];
  const float* lnb  = (const float*)d_in[18];
  const float* outw = (const float*)d_in[19];
  const float* outg = (const float*)d_in[20];
  const float* outb = (const float*)d_in[21];

  size_t need = (size_t)3 * NTOT * 4
              + (size_t)(2 * NPOS + NPOS + 1024 + 1024 + 512
                         + 2 * T_ * C_ + 2 * 9 * 1024 + 2 * 9 * 32) * 4
              + (size_t)8 * 4096 * 2;
  if (ws_size < need) return;

  float* R0f = (float*)d_ws;
  float* R1f = R0f + NTOT;
  float* R2f = R1f + NTOT;
  bh* R0b = (bh*)R0f; bh* R1b = (bh*)R1f; bh* R2b = (bh*)R2f;
  float* fbase = R0f + 3 * (size_t)NTOT;
  float* comb  = fbase;            // B*2*HT
  float* as_   = comb + 2 * NPOS;  // B*HT
  float* casum = as_ + NPOS;       // 1024
  float* camax = casum + 1024;     // 1024
  float* ac    = camax + 1024;     // 512
  float* ct    = ac + 512;         // 2*T*C
  float* Pg    = ct + 2 * T_ * C_; // 2*9*1024
  float* qg    = Pg + 2 * 9 * 1024;// 2*9*32
  bh* Wbf = (bh*)(qg + 2 * 9 * 32);// 8 slots * 4096 bf16

  prep<<<16, 256, 0, stream>>>(in_w, dwpw, dwg, d1pw, d1g, outw, outg, Wbf);
  ssmctA<<<2, 1024, 0, stream>>>(ssmA, ssmBv, Pg, qg);
  ssmctB<<<dim3(13, 2), 1024, 0, stream>>>(Pg, qg, ssmC, ct);
  // input proj: f32 in -> f32 out (X role -> R0)
  pwk<0, false, false, false, true, true, false><<<1550, 256, 0, stream>>>(
      x, Wbf + 0 * 4096, nullptr, nullptr, nullptr, R0f, nullptr,
      nullptr, nullptr, nullptr, nullptr, nullptr, nullptr, 0);

  // buffers rotate: half0: X=R0 -> X_out=R2 (f32,rev); half1: X=R2 -> X_out=R1 (bf16)
  auto run_half = [&](int hf, float* Xf, bh* D0, bh* D1, bh* B1, bh* B2,
                      void* Xout, bool outf32) {
    const float* dw0 = dwdw + (hf * 2 + 0) * C_ * 25;
    const float* dw1 = dwdw + (hf * 2 + 1) * C_ * 25;
    const float* b0  = dwb + (hf * 2 + 0) * C_;
    const float* b1w = dwb + (hf * 2 + 1) * C_;
    dw5dual<<<dim3(7, 512), 256, 0, stream>>>(Xf, dw0, dw1, D0, D1);
    // b1 = relu(bn(pw(D0))) -> B1
    pwk<1, false, false, false, false, false, false><<<1550, 256, 0, stream>>>(
        D0, Wbf + (1 + hf * 3) * 4096, b0, nullptr, nullptr, B1, nullptr,
        nullptr, nullptr, nullptr, nullptr, nullptr, nullptr, 0);
    // b2 = relu(bn(pw(D1))) -> B2 + comb
    pwk<1, false, true, false, false, false, false><<<1550, 256, 0, stream>>>(
        D1, Wbf + (2 + hf * 3) * 4096, b1w, nullptr, nullptr, B2, comb,
        nullptr, nullptr, nullptr, nullptr, nullptr, nullptr, 0);
    chanred<<<1024, 256, 0, stream>>>(B1, casum, camax);
    cafc<<<1, 512, 0, stream>>>(casum, camax, caw1 + hf * 4 * 64, caw2 + hf * 64 * 4, ac);
    conv7<<<248, 256, 0, stream>>>(comb, saw + hf * 98, as_);
    // fused: cb = sigmoid(bn(pw(dw1x3(b1^2*ac)))) -> SSM+LN+gate -> Xout
    if (outf32)
      pwk<2, false, false, true, false, true, true><<<1550, 256, 0, stream>>>(
          B1, Wbf + (3 + hf * 3) * 4096, d1b + hf * C_, ac, d1dw + hf * C_ * 3,
          Xout, nullptr, B2, as_, ct + hf * T_ * C_, ssmD + hf * C_,
          lng + hf * C_, lnb + hf * C_, hf == 0 ? 1 : 0);
    else
      pwk<2, false, false, true, false, false, true><<<1550, 256, 0, stream>>>(
          B1, Wbf + (3 + hf * 3) * 4096, d1b + hf * C_, ac, d1dw + hf * C_ * 3,
          Xout, nullptr, B2, as_, ct + hf * T_ * C_, ssmD + hf * C_,
          lng + hf * C_, lnb + hf * C_, hf == 0 ? 1 : 0);
  };

  // half 0: X=R0f; d0->R1b d1->R2b; b1->R0b; b2->R1b; X_out -> R2f (f32, rev)
  run_half(0, R0f, R1b, R2b, R0b, R1b, (void*)R2f, true);
  // half 1: X=R2f; d0->R0b d1->R1b; b1->R2b; b2->R0b; X_out -> R1b (bf16)
  run_half(1, R2f, R0b, R1b, R2b, R0b, (void*)R1b, false);
  // final pw: bf16 in (REV undo) -> f32 out + bn + relu
  pwk<1, true, false, false, false, true, false><<<1550, 256, 0, stream>>>(
      R1b, Wbf + 7 * 4096, outb, nullptr, nullptr, (float*)d_out, nullptr,
      nullptr, nullptr, nullptr, nullptr, nullptr, nullptr, 0);
}

// Round 16
// 417.887 us; speedup vs baseline: 1.0145x; 1.0145x over previous
//
#include <hip/hip_runtime.h>
#include <math.h>

#define DI __device__ __forceinline__

constexpr int B_ = 8, C_ = 64, H_ = 62, T_ = 400, S_ = 32;
constexpr int HT   = H_ * T_;      // 24800
constexpr int CHT  = C_ * HT;      // 1587200
constexpr int NPOS = B_ * HT;      // 198400
constexpr int NTOT = B_ * CHT;     // 12697600

typedef __attribute__((ext_vector_type(8))) short short8;
typedef __attribute__((ext_vector_type(4))) float float4v;
typedef unsigned short bh;

DI float sigmoidf_(float x) { return 1.f / (1.f + expf(-x)); }
DI float gelu_(float x) { return 0.5f * x * (1.f + erff(x * 0.70710678118654752f)); }

template<int ACT> DI float act_(float v) {
  if (ACT == 1) return fmaxf(v, 0.f);
  if (ACT == 2) return sigmoidf_(v);
  return v;
}

DI bh f2b(float f) {                        // fp32 -> bf16 RNE
  unsigned int u = __float_as_uint(f);
  u += 0x7FFFu + ((u >> 16) & 1u);
  return (bh)(u >> 16);
}
DI float b2f(bh u) { return __uint_as_float(((unsigned int)u) << 16); }
DI unsigned int pk2(float a, float b) {
  return (unsigned int)f2b(a) | ((unsigned int)f2b(b) << 16);
}

// ---------- prep: weights -> bf16 A-fragment layout, bn gain folded ----------
__global__ __launch_bounds__(256) void prep(const float* __restrict__ in_w,
    const float* __restrict__ dwpw, const float* __restrict__ dwg,
    const float* __restrict__ d1pw, const float* __restrict__ d1g,
    const float* __restrict__ outw, const float* __restrict__ outg,
    bh* __restrict__ wf) {
  int idx = blockIdx.x * 256 + threadIdx.x;     // 4096 fragments
  int lane = idx & 63, kc = (idx >> 6) & 1, w = (idx >> 7) & 3, slot = idx >> 9;
  const float* src; const float* g;
  switch (slot) {
    case 0: src = in_w;            g = nullptr;      break;
    case 1: src = dwpw + 0 * 4096; g = dwg + 0 * 64; break;
    case 2: src = dwpw + 1 * 4096; g = dwg + 1 * 64; break;
    case 3: src = d1pw + 0 * 4096; g = d1g + 0 * 64; break;
    case 4: src = dwpw + 2 * 4096; g = dwg + 2 * 64; break;
    case 5: src = dwpw + 3 * 4096; g = dwg + 3 * 64; break;
    case 6: src = d1pw + 1 * 4096; g = d1g + 1 * 64; break;
    default: src = outw;           g = outg;         break;
  }
  int o = w * 16 + (lane & 15);
  float gv = g ? g[o] : 1.f;
  unsigned int pack[4];
  #pragma unroll
  for (int h = 0; h < 4; ++h) {
    int c = kc * 32 + (lane >> 4) * 8 + h * 2;
    pack[h] = pk2(src[o * 64 + c] * gv, src[o * 64 + c + 1] * gv);
  }
  *(uint4*)&wf[idx * 8] = make_uint4(pack[0], pack[1], pack[2], pack[3]);
}

// ---------- pointwise 64x64 conv via MFMA (+ optional fused SSM/LN/gate) -----
// 1550 blocks x 256 thr; 128 pos x 64 out, K=64. X staged to LDS bf16 [p][c]
// (stride 72, XOR swizzle). K8F: epilogue = SSM pointwise + residual +
// channel-LayerNorm + spatial gate, ct read from GLOBAL transposed ct2[c2][t]
// (coalesced per 16-lane group; no LDS staging).
template<int ACT, bool REV, bool SPAT, bool DW13, bool INF32, bool OUTF32, bool K8F>
__global__ __launch_bounds__(256) void pwk(const void* __restrict__ in_,
    const bh* __restrict__ wf, const float* __restrict__ bb,
    const float* __restrict__ ac, const float* __restrict__ w3,
    void* __restrict__ out_, float* __restrict__ comb,
    const bh* __restrict__ b2g, const float* __restrict__ asg,
    const float* __restrict__ ctg, const float* __restrict__ Dg,
    const float* __restrict__ lngg, const float* __restrict__ lnbg, int rev) {
  constexpr int XB_B = 128 * 72 * 2;                    // 18432
  constexpr int RED_B = (K8F || SPAT) ? 4096 : 0;
  __shared__ __align__(16) char smr_[XB_B + RED_B];
  bh* Xb = (bh*)smr_;
  const int tid = threadIdx.x;
  const int lane = tid & 63;
  const int wv = tid >> 6;
  const int p0 = blockIdx.x * 128;
  // ---- stage X tile: thread = 4 positions x 8 channels
  {
    const int ps = (tid & 31) * 4;
    const int cs = (tid >> 5) * 8;
    const int p4 = p0 + ps;
    const int b = p4 / HT, ht = p4 - b * HT;
    const int row = ht / T_, t0 = ht - row * T_;
    float xv[8][4];
    if constexpr (INF32) {
      const float* rp0 = (const float*)in_ + b * CHT + row * T_;
      #pragma unroll
      for (int cj = 0; cj < 8; ++cj) {
        const float* rp = rp0 + (cs + cj) * HT;
        if constexpr (REV) {
          float4 u = *(const float4*)&rp[T_ - 4 - t0];
          xv[cj][0] = u.w; xv[cj][1] = u.z; xv[cj][2] = u.y; xv[cj][3] = u.x;
        } else {
          float4 u = *(const float4*)&rp[t0];
          xv[cj][0] = u.x; xv[cj][1] = u.y; xv[cj][2] = u.z; xv[cj][3] = u.w;
        }
      }
    } else if constexpr (DW13) {
      const bh* rp0 = (const bh*)in_ + b * CHT + row * T_;
      #pragma unroll
      for (int cj = 0; cj < 8; ++cj) {
        const int c = cs + cj;
        const bh* rp = rp0 + c * HT;
        ushort4 u = *(const ushort4*)&rp[t0];
        float x0 = b2f(u.x), x1 = b2f(u.y), x2 = b2f(u.z), x3 = b2f(u.w);
        float xm = (t0 > 0)      ? b2f(rp[t0 - 1]) : 0.f;
        float xp = (t0 < T_ - 4) ? b2f(rp[t0 + 4]) : 0.f;
        float s0 = xm * xm, s1 = x0 * x0, s2 = x1 * x1;
        float s3 = x2 * x2, s4 = x3 * x3, s5 = xp * xp;
        float acv = ac[b * 64 + c];
        float c0 = w3[c * 3 + 0] * acv, c1 = w3[c * 3 + 1] * acv,
              c2 = w3[c * 3 + 2] * acv;
        xv[cj][0] = c0 * s0 + c1 * s1 + c2 * s2;
        xv[cj][1] = c0 * s1 + c1 * s2 + c2 * s3;
        xv[cj][2] = c0 * s2 + c1 * s3 + c2 * s4;
        xv[cj][3] = c0 * s3 + c1 * s4 + c2 * s5;
      }
    } else {
      const bh* rp0 = (const bh*)in_ + b * CHT + row * T_;
      #pragma unroll
      for (int cj = 0; cj < 8; ++cj) {
        const bh* rp = rp0 + (cs + cj) * HT;
        ushort4 u;
        if constexpr (REV) {
          u = *(const ushort4*)&rp[T_ - 4 - t0];
          xv[cj][0] = b2f(u.w); xv[cj][1] = b2f(u.z);
          xv[cj][2] = b2f(u.y); xv[cj][3] = b2f(u.x);
        } else {
          u = *(const ushort4*)&rp[t0];
          xv[cj][0] = b2f(u.x); xv[cj][1] = b2f(u.y);
          xv[cj][2] = b2f(u.z); xv[cj][3] = b2f(u.w);
        }
      }
    }
    #pragma unroll
    for (int pi = 0; pi < 4; ++pi) {
      int r = ps + pi;
      int col = cs ^ (((r >> 2) & 7) << 3);       // swizzle (8-bh blocks)
      uint4 w4;
      w4.x = pk2(xv[0][pi], xv[1][pi]);
      w4.y = pk2(xv[2][pi], xv[3][pi]);
      w4.z = pk2(xv[4][pi], xv[5][pi]);
      w4.w = pk2(xv[6][pi], xv[7][pi]);
      *(uint4*)&Xb[r * 72 + col] = w4;
    }
  }
  // ---- A fragments (weights), coalesced 16B per lane
  short8 af0 = *(const short8*)(wf + ((wv * 2 + 0) * 64 + lane) * 8);
  short8 af1 = *(const short8*)(wf + ((wv * 2 + 1) * 64 + lane) * 8);
  const int m4 = (lane >> 4) * 4;
  float binit[4];
  #pragma unroll
  for (int j = 0; j < 4; ++j) binit[j] = bb ? bb[wv * 16 + m4 + j] : 0.f;
  __syncthreads();
  // ---- MFMA: 8 M-tiles (position groups) x 2 K-chunks
  float4v acc[8];
  #pragma unroll
  for (int nt = 0; nt < 8; ++nt) { acc[nt][0] = acc[nt][1] = acc[nt][2] = acc[nt][3] = 0.f; }
  #pragma unroll
  for (int nt = 0; nt < 8; ++nt) {
    int r = nt * 16 + (lane & 15);
    int sw = ((r >> 2) & 7) << 3;
    int cb0 = ((lane >> 4) * 8) ^ sw;
    int cb1 = (32 + (lane >> 4) * 8) ^ sw;
    short8 b0 = *(const short8*)&Xb[r * 72 + cb0];
    short8 b1 = *(const short8*)&Xb[r * 72 + cb1];
    acc[nt] = __builtin_amdgcn_mfma_f32_16x16x32_bf16(af0, b0, acc[nt], 0, 0, 0);
    acc[nt] = __builtin_amdgcn_mfma_f32_16x16x32_bf16(af1, b1, acc[nt], 0, 0, 0);
  }
  if constexpr (K8F) {
    // ========== fused SSM + LN + spatial gate epilogue (ct from global) =====
    float* redA = (float*)(smr_ + XB_B);     // [4][128]
    float* redB = redA + 512;                // [4][128]
    // v = cb + gelu(ct2[c2][t] + cb*D), in place over acc.
    // Each 16-lane group: c,h constant, t consecutive -> coalesced ct2 reads.
    #pragma unroll
    for (int nt = 0; nt < 8; ++nt) {
      int p = p0 + nt * 16 + (lane & 15);
      int b = p / HT, ht = p - b * HT;
      int h = ht / T_, t = ht - h * T_;
      #pragma unroll
      for (int j = 0; j < 4; ++j) {
        int c = wv * 16 + m4 + j;
        float cbv = act_<ACT>(acc[nt][j] + binit[j]);
        int c2 = (h - 2 * c) & 63;           // (62c+h) mod 64
        float u = ctg[c2 * T_ + t] + cbv * Dg[c2];
        acc[nt][j] = cbv + gelu_(u);
      }
    }
    // LN pass 1: mean over channels
    #pragma unroll
    for (int nt = 0; nt < 8; ++nt) {
      float s = acc[nt][0] + acc[nt][1] + acc[nt][2] + acc[nt][3];
      s += __shfl_xor(s, 16); s += __shfl_xor(s, 32);
      if (lane < 16) redA[wv * 128 + nt * 16 + lane] = s;
    }
    __syncthreads();
    float mu8[8];
    #pragma unroll
    for (int nt = 0; nt < 8; ++nt) {
      int q = nt * 16 + (lane & 15);
      mu8[nt] = (redA[q] + redA[128 + q] + redA[256 + q] + redA[384 + q])
                * (1.f / 64.f);
    }
    // LN pass 2: variance
    #pragma unroll
    for (int nt = 0; nt < 8; ++nt) {
      float d0 = acc[nt][0] - mu8[nt], d1 = acc[nt][1] - mu8[nt];
      float d2 = acc[nt][2] - mu8[nt], d3 = acc[nt][3] - mu8[nt];
      float qv = d0 * d0 + d1 * d1 + d2 * d2 + d3 * d3;
      qv += __shfl_xor(qv, 16); qv += __shfl_xor(qv, 32);
      if (lane < 16) redB[wv * 128 + nt * 16 + lane] = qv;
    }
    __syncthreads();
    float rstd8[8];
    #pragma unroll
    for (int nt = 0; nt < 8; ++nt) {
      int q = nt * 16 + (lane & 15);
      float Q = redB[q] + redB[128 + q] + redB[256 + q] + redB[384 + q];
      rstd8[nt] = rsqrtf(Q * (1.f / 64.f) + 1e-5f);
    }
    // gate + store (indices recomputed -> lower VGPR)
    #pragma unroll
    for (int nt = 0; nt < 8; ++nt) {
      int p = p0 + nt * 16 + (lane & 15);
      int b = p / HT, ht = p - b * HT;
      int h = ht / T_, t = ht - h * T_;
      float av = asg[p];
      int off = b * CHT + ht;
      int wof = b * CHT + (rev ? (h * T_ + T_ - 1 - t) : ht);
      #pragma unroll
      for (int j = 0; j < 4; ++j) {
        int c = wv * 16 + m4 + j;
        float y = (acc[nt][j] - mu8[nt]) * rstd8[nt] * lngg[c] + lnbg[c];
        float bv = b2f(b2g[off + c * HT]);
        float rr = y * sigmoidf_(bv * bv * av);
        if constexpr (OUTF32) ((float*)out_)[wof + c * HT] = rr;
        else                  ((bh*)out_)[wof + c * HT] = f2b(rr);
      }
    }
  } else {
    // ================= plain epilogue ======================================
    float psum[8], pmaxv[8];
    #pragma unroll
    for (int nt = 0; nt < 8; ++nt) {
      int n = nt * 16 + (lane & 15);
      int p = p0 + n;
      int b = p / HT, ht = p - b * HT;
      float s = 0.f, m = -3.4e38f;
      if constexpr (OUTF32) {
        float* op = (float*)out_ + b * CHT + ht + (wv * 16 + m4) * HT;
        #pragma unroll
        for (int j = 0; j < 4; ++j) {
          float r = act_<ACT>(acc[nt][j] + binit[j]);
          op[j * HT] = r;
          if constexpr (SPAT) { s += r; m = fmaxf(m, r); }
        }
      } else {
        bh* op = (bh*)out_ + b * CHT + ht + (wv * 16 + m4) * HT;
        #pragma unroll
        for (int j = 0; j < 4; ++j) {
          float r = act_<ACT>(acc[nt][j] + binit[j]);
          op[j * HT] = f2b(r);
          if constexpr (SPAT) { s += r; m = fmaxf(m, r); }
        }
      }
      if constexpr (SPAT) {
        s += __shfl_xor(s, 16); s += __shfl_xor(s, 32);
        m = fmaxf(m, __shfl_xor(m, 16)); m = fmaxf(m, __shfl_xor(m, 32));
        psum[nt] = s; pmaxv[nt] = m;
      }
    }
    if constexpr (SPAT) {
      float* redS = (float*)(smr_ + XB_B);   // [4][128]
      float* redM = redS + 512;
      if (lane < 16) {
        #pragma unroll
        for (int nt = 0; nt < 8; ++nt) {
          redS[wv * 128 + nt * 16 + lane] = psum[nt];
          redM[wv * 128 + nt * 16 + lane] = pmaxv[nt];
        }
      }
      __syncthreads();
      if (tid < 128) {
        float s = redS[tid] + redS[128 + tid] + redS[256 + tid] + redS[384 + tid];
        float m = fmaxf(fmaxf(redM[tid], redM[128 + tid]),
                        fmaxf(redM[256 + tid], redM[384 + tid]));
        int pp = p0 + tid;
        int b2i = pp / HT, ht2 = pp - b2i * HT;
        comb[b2i * 2 * HT + ht2] = s * (1.f / 64.f);
        comb[b2i * 2 * HT + HT + ht2] = m;
      }
    }
  }
}

// ---------- dual 5x5 depthwise conv, pad 2: f32 in, bf16 out ----------
__global__ __launch_bounds__(256) void dw5dual(const float* __restrict__ in,
    const float* __restrict__ w0_, const float* __restrict__ w1_,
    bh* __restrict__ out0, bh* __restrict__ out1) {
  const int bc = blockIdx.y;
  const int c = bc & 63;
  int task = blockIdx.x * 256 + threadIdx.x;
  if (task >= 62 * 25) return;             // 62 rows * 25 chunks of 16
  int h = task / 25;
  int t0 = (task - h * 25) << 4;
  const float* base = in + (size_t)bc * HT;
  const float* wp0 = w0_ + c * 25;
  const float* wp1 = w1_ + c * 25;
  float acc0[16], acc1[16];
  #pragma unroll
  for (int j = 0; j < 16; ++j) { acc0[j] = 0.f; acc1[j] = 0.f; }
  const bool fast = (t0 >= 4) && (t0 <= 380);
  #pragma unroll 1
  for (int u = 0; u < 5; ++u) {
    int hh = h + u - 2;
    if (hh < 0 || hh >= H_) continue;
    const float* row = base + hh * T_;
    float win[24];
    if (fast) {
      #pragma unroll
      for (int j = 0; j < 6; ++j)
        *(float4*)&win[4 * j] = *(const float4*)&row[t0 - 4 + 4 * j];
    } else {
      #pragma unroll
      for (int k = 0; k < 24; ++k) {
        int tt = t0 - 4 + k;
        win[k] = (tt >= 0 && tt < T_) ? row[tt] : 0.f;
      }
    }
    #pragma unroll
    for (int v = 0; v < 5; ++v) {
      float wa = wp0[u * 5 + v];            // uniform -> SGPR
      float wb = wp1[u * 5 + v];
      #pragma unroll
      for (int j = 0; j < 16; ++j) {
        float x = win[j + v + 2];
        acc0[j] += wa * x;
        acc1[j] += wb * x;
      }
    }
  }
  unsigned int pk0[8], pk1[8];
  #pragma unroll
  for (int j = 0; j < 8; ++j) {
    pk0[j] = pk2(acc0[2 * j], acc0[2 * j + 1]);
    pk1[j] = pk2(acc1[2 * j], acc1[2 * j + 1]);
  }
  bh* o0 = out0 + (size_t)bc * HT + h * T_ + t0;
  bh* o1 = out1 + (size_t)bc * HT + h * T_ + t0;
  *(uint4*)&o0[0] = make_uint4(pk0[0], pk0[1], pk0[2], pk0[3]);
  *(uint4*)&o0[8] = make_uint4(pk0[4], pk0[5], pk0[6], pk0[7]);
  *(uint4*)&o1[0] = make_uint4(pk1[0], pk1[1], pk1[2], pk1[3]);
  *(uint4*)&o1[8] = make_uint4(pk1[4], pk1[5], pk1[6], pk1[7]);
}

// ---------- channel attention: raw-sum+max over half a (H,T) plane (bf16) ----
__global__ __launch_bounds__(256) void chanred(const bh* __restrict__ in,
    float* __restrict__ sum_, float* __restrict__ max_) {
  int bc = blockIdx.x >> 1, hf = blockIdx.x & 1;
  const bh* base = in + (size_t)bc * HT + hf * (HT / 2);
  float s = 0.f, m = -3.4e38f;
  for (int i = threadIdx.x * 2; i < HT / 2; i += 512) {
    ushort2 q = *(const ushort2*)&base[i];
    float v0 = b2f(q.x), v1 = b2f(q.y);
    s += v0 + v1; m = fmaxf(m, fmaxf(v0, v1));
  }
  #pragma unroll
  for (int off = 32; off > 0; off >>= 1) {
    s += __shfl_down(s, off);
    m = fmaxf(m, __shfl_down(m, off));
  }
  __shared__ float ss[4], sm[4];
  int wv = threadIdx.x >> 6;
  if ((threadIdx.x & 63) == 0) { ss[wv] = s; sm[wv] = m; }
  __syncthreads();
  if (threadIdx.x == 0) {
    float S = ss[0] + ss[1] + ss[2] + ss[3];
    float M = fmaxf(fmaxf(sm[0], sm[1]), fmaxf(sm[2], sm[3]));
    sum_[hf * 512 + bc] = S;
    max_[hf * 512 + bc] = M;
  }
}

// ---------- channel attention FC: ac[b,c] = sigmoid(fc(avg)+fc(max)) ----------
__global__ __launch_bounds__(512) void cafc(const float* __restrict__ cs,
    const float* __restrict__ cm, const float* __restrict__ w1,
    const float* __restrict__ w2, float* __restrict__ ac) {
  __shared__ float sa[512], sx[512], hsum[8][4];
  int tid = threadIdx.x;
  sa[tid] = (cs[tid] + cs[512 + tid]) * (1.f / HT);
  sx[tid] = fmaxf(cm[tid], cm[512 + tid]);
  __syncthreads();
  if (tid < 32) {
    int b = tid >> 2, m = tid & 3;
    float s1 = 0.f, s2 = 0.f;
    #pragma unroll
    for (int cc = 0; cc < 64; ++cc) {
      float wv = w1[m * 64 + cc];
      s1 += sa[b * 64 + cc] * wv;
      s2 += sx[b * 64 + cc] * wv;
    }
    hsum[b][m] = fmaxf(s1, 0.f) + fmaxf(s2, 0.f);
  }
  __syncthreads();
  int b = tid >> 6, cc = tid & 63;
  float f = 0.f;
  #pragma unroll
  for (int m = 0; m < 4; ++m) f += hsum[b][m] * w2[cc * 4 + m];
  ac[tid] = sigmoidf_(f);
}

// ---------- 7x7 conv over 2 channels + sigmoid (LDS row-pair tile) ----------
__global__ __launch_bounds__(256) void conv7(const float* __restrict__ comb,
    const float* __restrict__ w, float* __restrict__ as_) {
  __shared__ float sm[2][8][408];
  __shared__ float sw[98];
  const int b = blockIdx.x / 31, hp = blockIdx.x % 31;
  const int h0 = hp * 2;
  const float* cb0 = comb + b * 2 * HT;
  const int tid = threadIdx.x;
  if (tid < 98) sw[tid] = w[tid];
  for (int e = tid; e < 2 * 8 * 408; e += 256) {
    int ci = e / 3264, rem = e - ci * 3264;
    int r = rem / 408, tt = rem - r * 408;
    int hh = h0 - 3 + r, t = tt - 4;
    float v = 0.f;
    if (hh >= 0 && hh < H_ && t >= 0 && t < T_) v = cb0[ci * HT + hh * T_ + t];
    sm[ci][r][tt] = v;
  }
  __syncthreads();
  for (int o = tid; o < 800; o += 256) {
    int oh = o / 400, ot = o - oh * 400;
    float acc = 0.f;
    #pragma unroll
    for (int ci = 0; ci < 2; ++ci)
      #pragma unroll
      for (int u = 0; u < 7; ++u)
        #pragma unroll
        for (int v = 0; v < 7; ++v)
          acc += sw[ci * 49 + u * 7 + v] * sm[ci][oh + u][ot + v + 1];
    as_[b * HT + (h0 + oh) * T_ + ot] = sigmoidf_(acc);
  }
}

// ---------- ssmctA: build P[i]=A^(2^i), q[i]=s_(2^i) tables (per half) ----------
__global__ __launch_bounds__(1024) void ssmctA(const float* __restrict__ A_,
    const float* __restrict__ Bv_, float* __restrict__ Pg, float* __restrict__ qg) {
  const int hf = blockIdx.x;
  const float* A = A_ + hf * 1024;
  const float* Bv = Bv_ + hf * 32;
  __shared__ float Pbuf[2][32 * 33];
  __shared__ float qbuf[2][32];
  const int tid = threadIdx.x;
  float* Pc = Pbuf[0]; float* Pn = Pbuf[1];
  float* qc = qbuf[0]; float* qn = qbuf[1];
  Pc[(tid >> 5) * 33 + (tid & 31)] = A[tid];
  if (tid < 32) qc[tid] = Bv[tid];
  __syncthreads();
  for (int i = 0; i < 9; ++i) {
    Pg[(hf * 9 + i) * 1024 + tid] = Pc[(tid >> 5) * 33 + (tid & 31)];
    if (tid < 32) qg[(hf * 9 + i) * 32 + tid] = qc[tid];
    if (i == 8) break;
    const int r = tid >> 5, cc = tid & 31;
    float s0 = 0.f, s1 = 0.f, s2 = 0.f, s3 = 0.f;
    #pragma unroll
    for (int k = 0; k < 32; k += 4) {
      s0 += Pc[r * 33 + k + 0] * Pc[(k + 0) * 33 + cc];
      s1 += Pc[r * 33 + k + 1] * Pc[(k + 1) * 33 + cc];
      s2 += Pc[r * 33 + k + 2] * Pc[(k + 2) * 33 + cc];
      s3 += Pc[r * 33 + k + 3] * Pc[(k + 3) * 33 + cc];
    }
    float qv = 0.f;
    if (tid < 32) {
      float a0 = 0.f, a1 = 0.f;
      #pragma unroll
      for (int k = 0; k < 32; k += 2) {
        a0 += Pc[tid * 33 + k] * qc[k];
        a1 += Pc[tid * 33 + k + 1] * qc[k + 1];
      }
      qv = qc[tid] + a0 + a1;
    }
    Pn[r * 33 + cc] = s0 + s1 + s2 + s3;
    if (tid < 32) qn[tid] = qv;
    __syncthreads();
    float* tp = Pc; Pc = Pn; Pn = tp;
    float* tq = qc; qc = qn; qn = tq;
  }
}

// ---------- ssmctB: per-t bit-walk; ct2 written TRANSPOSED [c2][t] ----------
__global__ __launch_bounds__(1024) void ssmctB(const float* __restrict__ Pg,
    const float* __restrict__ qg, const float* __restrict__ Cm_,
    float* __restrict__ ct) {
  const int hf = blockIdx.y;
  __shared__ float P[9][32][33];
  __shared__ float q[9][32];
  __shared__ float Cs[32 * 64];
  __shared__ float st[32][33];
  const int tid = threadIdx.x;
  #pragma unroll
  for (int i = 0; i < 9; ++i) {
    int rem = tid;
    P[i][rem >> 5][rem & 31] = Pg[(hf * 9 + i) * 1024 + rem];
  }
  if (tid < 9 * 32) q[tid >> 5][tid & 31] = qg[hf * 9 * 32 + tid];
  for (int e = tid; e < 2048; e += 1024) Cs[e] = Cm_[hf * 2048 + e];
  __syncthreads();
  const int grp = tid >> 5, j = tid & 31;
  const int tIdx = blockIdx.x * 32 + grp;
  const int n = tIdx + 1;
  float s = 0.f;
  #pragma unroll
  for (int i = 0; i < 9; ++i) {
    st[grp][j] = s;                        // in-wave exchange (no barrier)
    float a0 = q[i][j], a1 = 0.f;
    #pragma unroll
    for (int k = 0; k < 32; k += 2) {
      a0 += P[i][j][k] * st[grp][k];
      a1 += P[i][j][k + 1] * st[grp][k + 1];
    }
    s = ((n >> i) & 1) ? (a0 + a1) : s;
  }
  st[grp][j] = s;
  __syncthreads();
  #pragma unroll
  for (int e0 = 0; e0 < 2048; e0 += 1024) {
    int e = e0 + tid;
    int ts = e >> 6, c = e & 63;
    float a0 = 0.f, a1 = 0.f;
    #pragma unroll
    for (int k = 0; k < 32; k += 2) {
      a0 += st[ts][k] * Cs[k * 64 + c];
      a1 += st[ts][k + 1] * Cs[(k + 1) * 64 + c];
    }
    int tg = blockIdx.x * 32 + ts;
    if (tg < T_) ct[((size_t)hf * 64 + c) * T_ + tg] = a0 + a1;   // [c][t]
  }
}

extern "C" void kernel_launch(void* const* d_in, const int* in_sizes, int n_in,
                              void* d_out, int out_size, void* d_ws, size_t ws_size,
                              hipStream_t stream) {
  const float* x    = (const float*)d_in[0];
  const float* in_w = (const float*)d_in[1];
  const float* dwdw = (const float*)d_in[2];
  const float* dwpw = (const float*)d_in[3];
  const float* dwg  = (const float*)d_in[4];
  const float* dwb  = (const float*)d_in[5];
  const float* caw1 = (const float*)d_in[6];
  const float* caw2 = (const float*)d_in[7];
  const float* saw  = (const float*)d_in[8];
  const float* d1dw = (const float*)d_in[9];
  const float* d1pw = (const float*)d_in[10];
  const float* d1g  = (const float*)d_in[11];
  const float* d1b  = (const float*)d_in[12];
  const float* ssmA = (const float*)d_in[13];
  const float* ssmBv= (const float*)d_in[14];
  const float* ssmC = (const float*)d_in[15];
  const float* ssmD = (const float*)d_in[16];
  const float* lng  = (const float*)d_in[17];
  const float* lnb  = (const float*)d_in[18];
  const float* outw = (const float*)d_in[19];
  const float* outg = (const float*)d_in[20];
  const float* outb = (const float*)d_in[21];

  size_t need = (size_t)3 * NTOT * 4
              + (size_t)(2 * NPOS + NPOS + 1024 + 1024 + 512
                         + 2 * T_ * C_ + 2 * 9 * 1024 + 2 * 9 * 32) * 4
              + (size_t)8 * 4096 * 2;
  if (ws_size < need) return;

  float* R0f = (float*)d_ws;
  float* R1f = R0f + NTOT;
  float* R2f = R1f + NTOT;
  bh* R0b = (bh*)R0f; bh* R1b = (bh*)R1f; bh* R2b = (bh*)R2f;
  float* fbase = R0f + 3 * (size_t)NTOT;
  float* comb  = fbase;            // B*2*HT
  float* as_   = comb + 2 * NPOS;  // B*HT
  float* casum = as_ + NPOS;       // 1024
  float* camax = casum + 1024;     // 1024
  float* ac    = camax + 1024;     // 512
  float* ct    = ac + 512;         // 2*64*T (transposed [c][t])
  float* Pg    = ct + 2 * T_ * C_; // 2*9*1024
  float* qg    = Pg + 2 * 9 * 1024;// 2*9*32
  bh* Wbf = (bh*)(qg + 2 * 9 * 32);// 8 slots * 4096 bf16

  prep<<<16, 256, 0, stream>>>(in_w, dwpw, dwg, d1pw, d1g, outw, outg, Wbf);
  ssmctA<<<2, 1024, 0, stream>>>(ssmA, ssmBv, Pg, qg);
  ssmctB<<<dim3(13, 2), 1024, 0, stream>>>(Pg, qg, ssmC, ct);
  // input proj: f32 in -> f32 out (X role -> R0)
  pwk<0, false, false, false, true, true, false><<<1550, 256, 0, stream>>>(
      x, Wbf + 0 * 4096, nullptr, nullptr, nullptr, R0f, nullptr,
      nullptr, nullptr, nullptr, nullptr, nullptr, nullptr, 0);

  auto run_half = [&](int hf, float* Xf, bh* D0, bh* D1, bh* B1, bh* B2,
                      void* Xout, bool outf32) {
    const float* dw0 = dwdw + (hf * 2 + 0) * C_ * 25;
    const float* dw1 = dwdw + (hf * 2 + 1) * C_ * 25;
    const float* b0  = dwb + (hf * 2 + 0) * C_;
    const float* b1w = dwb + (hf * 2 + 1) * C_;
    dw5dual<<<dim3(7, 512), 256, 0, stream>>>(Xf, dw0, dw1, D0, D1);
    // b1 = relu(bn(pw(D0))) -> B1
    pwk<1, false, false, false, false, false, false><<<1550, 256, 0, stream>>>(
        D0, Wbf + (1 + hf * 3) * 4096, b0, nullptr, nullptr, B1, nullptr,
        nullptr, nullptr, nullptr, nullptr, nullptr, nullptr, 0);
    // b2 = relu(bn(pw(D1))) -> B2 + comb
    pwk<1, false, true, false, false, false, false><<<1550, 256, 0, stream>>>(
        D1, Wbf + (2 + hf * 3) * 4096, b1w, nullptr, nullptr, B2, comb,
        nullptr, nullptr, nullptr, nullptr, nullptr, nullptr, 0);
    chanred<<<1024, 256, 0, stream>>>(B1, casum, camax);
    cafc<<<1, 512, 0, stream>>>(casum, camax, caw1 + hf * 4 * 64, caw2 + hf * 64 * 4, ac);
    conv7<<<248, 256, 0, stream>>>(comb, saw + hf * 98, as_);
    // fused: cb = sigmoid(bn(pw(dw1x3(b1^2*ac)))) -> SSM+LN+gate -> Xout
    if (outf32)
      pwk<2, false, false, true, false, true, true><<<1550, 256, 0, stream>>>(
          B1, Wbf + (3 + hf * 3) * 4096, d1b + hf * C_, ac, d1dw + hf * C_ * 3,
          Xout, nullptr, B2, as_, ct + hf * 64 * T_, ssmD + hf * C_,
          lng + hf * C_, lnb + hf * C_, hf == 0 ? 1 : 0);
    else
      pwk<2, false, false, true, false, false, true><<<1550, 256, 0, stream>>>(
          B1, Wbf + (3 + hf * 3) * 4096, d1b + hf * C_, ac, d1dw + hf * C_ * 3,
          Xout, nullptr, B2, as_, ct + hf * 64 * T_, ssmD + hf * C_,
          lng + hf * C_, lnb + hf * C_, hf == 0 ? 1 : 0);
  };

  // half 0: X=R0f; d0->R1b d1->R2b; b1->R0b; b2->R1b; X_out -> R2f (f32, rev)
  run_half(0, R0f, R1b, R2b, R0b, R1b, (void*)R2f, true);
  // half 1: X=R2f; d0->R0b d1->R1b; b1->R2b; b2->R0b; X_out -> R1b (bf16)
  run_half(1, R2f, R0b, R1b, R2b, R0b, (void*)R1b, false);
  // final pw: bf16 in (REV undo) -> f32 out + bn + relu
  pwk<1, true, false, false, false, true, false><<<1550, 256, 0, stream>>>(
      R1b, Wbf + 7 * 4096, outb, nullptr, nullptr, (float*)d_out, nullptr,
      nullptr, nullptr, nullptr, nullptr, nullptr, nullptr, 0);
}

// Round 17
// 391.069 us; speedup vs baseline: 1.0840x; 1.0686x over previous
//
#include <hip/hip_runtime.h>
#include <math.h>

#define DI __device__ __forceinline__

constexpr int B_ = 8, C_ = 64, H_ = 62, T_ = 400, S_ = 32;
constexpr int HT   = H_ * T_;      // 24800
constexpr int CHT  = C_ * HT;      // 1587200
constexpr int NPOS = B_ * HT;      // 198400
constexpr int NTOT = B_ * CHT;     // 12697600

typedef __attribute__((ext_vector_type(8))) short short8;
typedef __attribute__((ext_vector_type(4))) float float4v;
typedef unsigned short bh;

DI float sigmoidf_(float x) { return 1.f / (1.f + expf(-x)); }
DI float gelu_(float x) { return 0.5f * x * (1.f + erff(x * 0.70710678118654752f)); }

template<int ACT> DI float act_(float v) {
  if (ACT == 1) return fmaxf(v, 0.f);
  if (ACT == 2) return sigmoidf_(v);
  return v;
}

DI bh f2b(float f) {                        // fp32 -> bf16 RNE
  unsigned int u = __float_as_uint(f);
  u += 0x7FFFu + ((u >> 16) & 1u);
  return (bh)(u >> 16);
}
DI float b2f(bh u) { return __uint_as_float(((unsigned int)u) << 16); }
DI unsigned int pk2(float a, float b) {
  return (unsigned int)f2b(a) | ((unsigned int)f2b(b) << 16);
}

// ---------- prep: weights -> bf16 A-fragment layout, bn gain folded ----------
__global__ __launch_bounds__(256) void prep(const float* __restrict__ in_w,
    const float* __restrict__ dwpw, const float* __restrict__ dwg,
    const float* __restrict__ d1pw, const float* __restrict__ d1g,
    const float* __restrict__ outw, const float* __restrict__ outg,
    bh* __restrict__ wf) {
  int idx = blockIdx.x * 256 + threadIdx.x;     // 4096 fragments
  int lane = idx & 63, kc = (idx >> 6) & 1, w = (idx >> 7) & 3, slot = idx >> 9;
  const float* src; const float* g;
  switch (slot) {
    case 0: src = in_w;            g = nullptr;      break;
    case 1: src = dwpw + 0 * 4096; g = dwg + 0 * 64; break;
    case 2: src = dwpw + 1 * 4096; g = dwg + 1 * 64; break;
    case 3: src = d1pw + 0 * 4096; g = d1g + 0 * 64; break;
    case 4: src = dwpw + 2 * 4096; g = dwg + 2 * 64; break;
    case 5: src = dwpw + 3 * 4096; g = dwg + 3 * 64; break;
    case 6: src = d1pw + 1 * 4096; g = d1g + 1 * 64; break;
    default: src = outw;           g = outg;         break;
  }
  int o = w * 16 + (lane & 15);
  float gv = g ? g[o] : 1.f;
  unsigned int pack[4];
  #pragma unroll
  for (int h = 0; h < 4; ++h) {
    int c = kc * 32 + (lane >> 4) * 8 + h * 2;
    pack[h] = pk2(src[o * 64 + c] * gv, src[o * 64 + c + 1] * gv);
  }
  *(uint4*)&wf[idx * 8] = make_uint4(pack[0], pack[1], pack[2], pack[3]);
}

// ---------- pointwise 64x64 conv via MFMA (generic) ----------
// 1550 blocks x 256 thr; 128 pos x 64 out, K=64. X staged to LDS bf16 [p][c]
// (stride 72, XOR swizzle); thread stages 4 pos x 8 ch.
template<int ACT, bool REV, bool SPAT, bool DW13, bool INF32, bool OUTF32>
__global__ __launch_bounds__(256) void pwk(const void* __restrict__ in_,
    const bh* __restrict__ wf, const float* __restrict__ bb,
    const float* __restrict__ ac, const float* __restrict__ w3,
    void* __restrict__ out_, float* __restrict__ comb) {
  __shared__ bh Xb[128 * 72];
  const int tid = threadIdx.x;
  const int lane = tid & 63;
  const int wv = tid >> 6;
  const int p0 = blockIdx.x * 128;
  {
    const int ps = (tid & 31) * 4;
    const int cs = (tid >> 5) * 8;
    const int p4 = p0 + ps;
    const int b = p4 / HT, ht = p4 - b * HT;
    const int row = ht / T_, t0 = ht - row * T_;
    float xv[8][4];
    if constexpr (INF32) {
      const float* rp0 = (const float*)in_ + b * CHT + row * T_;
      #pragma unroll
      for (int cj = 0; cj < 8; ++cj) {
        const float* rp = rp0 + (cs + cj) * HT;
        if constexpr (REV) {
          float4 u = *(const float4*)&rp[T_ - 4 - t0];
          xv[cj][0] = u.w; xv[cj][1] = u.z; xv[cj][2] = u.y; xv[cj][3] = u.x;
        } else {
          float4 u = *(const float4*)&rp[t0];
          xv[cj][0] = u.x; xv[cj][1] = u.y; xv[cj][2] = u.z; xv[cj][3] = u.w;
        }
      }
    } else if constexpr (DW13) {
      const bh* rp0 = (const bh*)in_ + b * CHT + row * T_;
      #pragma unroll
      for (int cj = 0; cj < 8; ++cj) {
        const int c = cs + cj;
        const bh* rp = rp0 + c * HT;
        ushort4 u = *(const ushort4*)&rp[t0];
        float x0 = b2f(u.x), x1 = b2f(u.y), x2 = b2f(u.z), x3 = b2f(u.w);
        float xm = (t0 > 0)      ? b2f(rp[t0 - 1]) : 0.f;
        float xp = (t0 < T_ - 4) ? b2f(rp[t0 + 4]) : 0.f;
        float s0 = xm * xm, s1 = x0 * x0, s2 = x1 * x1;
        float s3 = x2 * x2, s4 = x3 * x3, s5 = xp * xp;
        float acv = ac[b * 64 + c];
        float c0 = w3[c * 3 + 0] * acv, c1 = w3[c * 3 + 1] * acv,
              c2 = w3[c * 3 + 2] * acv;
        xv[cj][0] = c0 * s0 + c1 * s1 + c2 * s2;
        xv[cj][1] = c0 * s1 + c1 * s2 + c2 * s3;
        xv[cj][2] = c0 * s2 + c1 * s3 + c2 * s4;
        xv[cj][3] = c0 * s3 + c1 * s4 + c2 * s5;
      }
    } else {
      const bh* rp0 = (const bh*)in_ + b * CHT + row * T_;
      #pragma unroll
      for (int cj = 0; cj < 8; ++cj) {
        const bh* rp = rp0 + (cs + cj) * HT;
        ushort4 u;
        if constexpr (REV) {
          u = *(const ushort4*)&rp[T_ - 4 - t0];
          xv[cj][0] = b2f(u.w); xv[cj][1] = b2f(u.z);
          xv[cj][2] = b2f(u.y); xv[cj][3] = b2f(u.x);
        } else {
          u = *(const ushort4*)&rp[t0];
          xv[cj][0] = b2f(u.x); xv[cj][1] = b2f(u.y);
          xv[cj][2] = b2f(u.z); xv[cj][3] = b2f(u.w);
        }
      }
    }
    #pragma unroll
    for (int pi = 0; pi < 4; ++pi) {
      int r = ps + pi;
      int col = cs ^ (((r >> 2) & 7) << 3);       // swizzle (8-bh blocks)
      uint4 w4;
      w4.x = pk2(xv[0][pi], xv[1][pi]);
      w4.y = pk2(xv[2][pi], xv[3][pi]);
      w4.z = pk2(xv[4][pi], xv[5][pi]);
      w4.w = pk2(xv[6][pi], xv[7][pi]);
      *(uint4*)&Xb[r * 72 + col] = w4;
    }
  }
  short8 af0 = *(const short8*)(wf + ((wv * 2 + 0) * 64 + lane) * 8);
  short8 af1 = *(const short8*)(wf + ((wv * 2 + 1) * 64 + lane) * 8);
  const int m4 = (lane >> 4) * 4;
  float binit[4];
  #pragma unroll
  for (int j = 0; j < 4; ++j) binit[j] = bb ? bb[wv * 16 + m4 + j] : 0.f;
  __syncthreads();
  float4v acc[8];
  #pragma unroll
  for (int nt = 0; nt < 8; ++nt) { acc[nt][0] = acc[nt][1] = acc[nt][2] = acc[nt][3] = 0.f; }
  #pragma unroll
  for (int nt = 0; nt < 8; ++nt) {
    int r = nt * 16 + (lane & 15);
    int sw = ((r >> 2) & 7) << 3;
    int cb0 = ((lane >> 4) * 8) ^ sw;
    int cb1 = (32 + (lane >> 4) * 8) ^ sw;
    short8 b0 = *(const short8*)&Xb[r * 72 + cb0];
    short8 b1 = *(const short8*)&Xb[r * 72 + cb1];
    acc[nt] = __builtin_amdgcn_mfma_f32_16x16x32_bf16(af0, b0, acc[nt], 0, 0, 0);
    acc[nt] = __builtin_amdgcn_mfma_f32_16x16x32_bf16(af1, b1, acc[nt], 0, 0, 0);
  }
  float psum[8], pmaxv[8];
  #pragma unroll
  for (int nt = 0; nt < 8; ++nt) {
    int n = nt * 16 + (lane & 15);
    int p = p0 + n;
    int b = p / HT, ht = p - b * HT;
    float s = 0.f, m = -3.4e38f;
    if constexpr (OUTF32) {
      float* op = (float*)out_ + b * CHT + ht + (wv * 16 + m4) * HT;
      #pragma unroll
      for (int j = 0; j < 4; ++j) {
        float r = act_<ACT>(acc[nt][j] + binit[j]);
        op[j * HT] = r;
        if constexpr (SPAT) { s += r; m = fmaxf(m, r); }
      }
    } else {
      bh* op = (bh*)out_ + b * CHT + ht + (wv * 16 + m4) * HT;
      #pragma unroll
      for (int j = 0; j < 4; ++j) {
        float r = act_<ACT>(acc[nt][j] + binit[j]);
        op[j * HT] = f2b(r);
        if constexpr (SPAT) { s += r; m = fmaxf(m, r); }
      }
    }
    if constexpr (SPAT) {
      s += __shfl_xor(s, 16); s += __shfl_xor(s, 32);
      m = fmaxf(m, __shfl_xor(m, 16)); m = fmaxf(m, __shfl_xor(m, 32));
      psum[nt] = s; pmaxv[nt] = m;
    }
  }
  if constexpr (SPAT) {
    __shared__ float redS[4][128], redM[4][128];
    if (lane < 16) {
      #pragma unroll
      for (int nt = 0; nt < 8; ++nt) {
        redS[wv][nt * 16 + lane] = psum[nt];
        redM[wv][nt * 16 + lane] = pmaxv[nt];
      }
    }
    __syncthreads();
    if (tid < 128) {
      float s = redS[0][tid] + redS[1][tid] + redS[2][tid] + redS[3][tid];
      float m = fmaxf(fmaxf(redM[0][tid], redM[1][tid]),
                      fmaxf(redM[2][tid], redM[3][tid]));
      int pp = p0 + tid;
      int b2 = pp / HT, ht2 = pp - b2 * HT;
      comb[b2 * 2 * HT + ht2] = s * (1.f / 64.f);
      comb[b2 * 2 * HT + HT + ht2] = m;
    }
  }
}

// ---------- merged b1+b2 pointwise conv (3100 blocks; >=1550 -> b2+SPAT) -----
__global__ __launch_bounds__(256) void pwk_bb(const bh* __restrict__ inA,
    const bh* __restrict__ inB, const bh* __restrict__ wfA,
    const bh* __restrict__ wfB, const float* __restrict__ bbA,
    const float* __restrict__ bbB, bh* __restrict__ outA,
    bh* __restrict__ outB, float* __restrict__ comb) {
  __shared__ bh Xb[128 * 72];
  const int tid = threadIdx.x;
  const int lane = tid & 63;
  const int wv = tid >> 6;
  const bool sec = blockIdx.x >= 1550;
  const bh* in_ = sec ? inB : inA;
  const bh* wf = sec ? wfB : wfA;
  const float* bb = sec ? bbB : bbA;
  bh* out_ = sec ? outB : outA;
  const int p0 = (blockIdx.x - (sec ? 1550 : 0)) * 128;
  {
    const int ps = (tid & 31) * 4;
    const int cs = (tid >> 5) * 8;
    const int p4 = p0 + ps;
    const int b = p4 / HT, ht = p4 - b * HT;
    const int row = ht / T_, t0 = ht - row * T_;
    const bh* rp0 = in_ + b * CHT + row * T_;
    float xv[8][4];
    #pragma unroll
    for (int cj = 0; cj < 8; ++cj) {
      const bh* rp = rp0 + (cs + cj) * HT;
      ushort4 u = *(const ushort4*)&rp[t0];
      xv[cj][0] = b2f(u.x); xv[cj][1] = b2f(u.y);
      xv[cj][2] = b2f(u.z); xv[cj][3] = b2f(u.w);
    }
    #pragma unroll
    for (int pi = 0; pi < 4; ++pi) {
      int r = ps + pi;
      int col = cs ^ (((r >> 2) & 7) << 3);
      uint4 w4;
      w4.x = pk2(xv[0][pi], xv[1][pi]);
      w4.y = pk2(xv[2][pi], xv[3][pi]);
      w4.z = pk2(xv[4][pi], xv[5][pi]);
      w4.w = pk2(xv[6][pi], xv[7][pi]);
      *(uint4*)&Xb[r * 72 + col] = w4;
    }
  }
  short8 af0 = *(const short8*)(wf + ((wv * 2 + 0) * 64 + lane) * 8);
  short8 af1 = *(const short8*)(wf + ((wv * 2 + 1) * 64 + lane) * 8);
  const int m4 = (lane >> 4) * 4;
  float binit[4];
  #pragma unroll
  for (int j = 0; j < 4; ++j) binit[j] = bb[wv * 16 + m4 + j];
  __syncthreads();
  float4v acc[8];
  #pragma unroll
  for (int nt = 0; nt < 8; ++nt) { acc[nt][0] = acc[nt][1] = acc[nt][2] = acc[nt][3] = 0.f; }
  #pragma unroll
  for (int nt = 0; nt < 8; ++nt) {
    int r = nt * 16 + (lane & 15);
    int sw = ((r >> 2) & 7) << 3;
    int cb0 = ((lane >> 4) * 8) ^ sw;
    int cb1 = (32 + (lane >> 4) * 8) ^ sw;
    short8 b0 = *(const short8*)&Xb[r * 72 + cb0];
    short8 b1 = *(const short8*)&Xb[r * 72 + cb1];
    acc[nt] = __builtin_amdgcn_mfma_f32_16x16x32_bf16(af0, b0, acc[nt], 0, 0, 0);
    acc[nt] = __builtin_amdgcn_mfma_f32_16x16x32_bf16(af1, b1, acc[nt], 0, 0, 0);
  }
  float psum[8], pmaxv[8];
  #pragma unroll
  for (int nt = 0; nt < 8; ++nt) {
    int n = nt * 16 + (lane & 15);
    int p = p0 + n;
    int b = p / HT, ht = p - b * HT;
    float s = 0.f, m = -3.4e38f;
    bh* op = out_ + b * CHT + ht + (wv * 16 + m4) * HT;
    #pragma unroll
    for (int j = 0; j < 4; ++j) {
      float r = fmaxf(acc[nt][j] + binit[j], 0.f);
      op[j * HT] = f2b(r);
      s += r; m = fmaxf(m, r);
    }
    s += __shfl_xor(s, 16); s += __shfl_xor(s, 32);
    m = fmaxf(m, __shfl_xor(m, 16)); m = fmaxf(m, __shfl_xor(m, 32));
    psum[nt] = s; pmaxv[nt] = m;
  }
  __shared__ float redS[4][128], redM[4][128];
  if (lane < 16) {
    #pragma unroll
    for (int nt = 0; nt < 8; ++nt) {
      redS[wv][nt * 16 + lane] = psum[nt];
      redM[wv][nt * 16 + lane] = pmaxv[nt];
    }
  }
  __syncthreads();
  if (sec && tid < 128) {
    float s = redS[0][tid] + redS[1][tid] + redS[2][tid] + redS[3][tid];
    float m = fmaxf(fmaxf(redM[0][tid], redM[1][tid]),
                    fmaxf(redM[2][tid], redM[3][tid]));
    int pp = p0 + tid;
    int b2 = pp / HT, ht2 = pp - b2 * HT;
    comb[b2 * 2 * HT + ht2] = s * (1.f / 64.f);
    comb[b2 * 2 * HT + HT + ht2] = m;
  }
}

// ---------- dual 5x5 depthwise conv, pad 2: f32 in, bf16 out ----------
__global__ __launch_bounds__(256) void dw5dual(const float* __restrict__ in,
    const float* __restrict__ w0_, const float* __restrict__ w1_,
    bh* __restrict__ out0, bh* __restrict__ out1) {
  const int bc = blockIdx.y;
  const int c = bc & 63;
  int task = blockIdx.x * 256 + threadIdx.x;
  if (task >= 62 * 25) return;             // 62 rows * 25 chunks of 16
  int h = task / 25;
  int t0 = (task - h * 25) << 4;
  const float* base = in + (size_t)bc * HT;
  const float* wp0 = w0_ + c * 25;
  const float* wp1 = w1_ + c * 25;
  float acc0[16], acc1[16];
  #pragma unroll
  for (int j = 0; j < 16; ++j) { acc0[j] = 0.f; acc1[j] = 0.f; }
  const bool fast = (t0 >= 4) && (t0 <= 380);
  #pragma unroll 1
  for (int u = 0; u < 5; ++u) {
    int hh = h + u - 2;
    if (hh < 0 || hh >= H_) continue;
    const float* row = base + hh * T_;
    float win[24];
    if (fast) {
      #pragma unroll
      for (int j = 0; j < 6; ++j)
        *(float4*)&win[4 * j] = *(const float4*)&row[t0 - 4 + 4 * j];
    } else {
      #pragma unroll
      for (int k = 0; k < 24; ++k) {
        int tt = t0 - 4 + k;
        win[k] = (tt >= 0 && tt < T_) ? row[tt] : 0.f;
      }
    }
    #pragma unroll
    for (int v = 0; v < 5; ++v) {
      float wa = wp0[u * 5 + v];            // uniform -> SGPR
      float wb = wp1[u * 5 + v];
      #pragma unroll
      for (int j = 0; j < 16; ++j) {
        float x = win[j + v + 2];
        acc0[j] += wa * x;
        acc1[j] += wb * x;
      }
    }
  }
  unsigned int pk0[8], pk1[8];
  #pragma unroll
  for (int j = 0; j < 8; ++j) {
    pk0[j] = pk2(acc0[2 * j], acc0[2 * j + 1]);
    pk1[j] = pk2(acc1[2 * j], acc1[2 * j + 1]);
  }
  bh* o0 = out0 + (size_t)bc * HT + h * T_ + t0;
  bh* o1 = out1 + (size_t)bc * HT + h * T_ + t0;
  *(uint4*)&o0[0] = make_uint4(pk0[0], pk0[1], pk0[2], pk0[3]);
  *(uint4*)&o0[8] = make_uint4(pk0[4], pk0[5], pk0[6], pk0[7]);
  *(uint4*)&o1[0] = make_uint4(pk1[0], pk1[1], pk1[2], pk1[3]);
  *(uint4*)&o1[8] = make_uint4(pk1[4], pk1[5], pk1[6], pk1[7]);
}

// ---------- channel attention: raw-sum+max over half a (H,T) plane (bf16) ----
__global__ __launch_bounds__(256) void chanred(const bh* __restrict__ in,
    float* __restrict__ sum_, float* __restrict__ max_) {
  int bc = blockIdx.x >> 1, hf = blockIdx.x & 1;
  const bh* base = in + (size_t)bc * HT + hf * (HT / 2);
  float s = 0.f, m = -3.4e38f;
  for (int i = threadIdx.x * 2; i < HT / 2; i += 512) {
    ushort2 q = *(const ushort2*)&base[i];
    float v0 = b2f(q.x), v1 = b2f(q.y);
    s += v0 + v1; m = fmaxf(m, fmaxf(v0, v1));
  }
  #pragma unroll
  for (int off = 32; off > 0; off >>= 1) {
    s += __shfl_down(s, off);
    m = fmaxf(m, __shfl_down(m, off));
  }
  __shared__ float ss[4], sm[4];
  int wv = threadIdx.x >> 6;
  if ((threadIdx.x & 63) == 0) { ss[wv] = s; sm[wv] = m; }
  __syncthreads();
  if (threadIdx.x == 0) {
    float S = ss[0] + ss[1] + ss[2] + ss[3];
    float M = fmaxf(fmaxf(sm[0], sm[1]), fmaxf(sm[2], sm[3]));
    sum_[hf * 512 + bc] = S;
    max_[hf * 512 + bc] = M;
  }
}

// ---------- channel attention FC: ac[b,c] = sigmoid(fc(avg)+fc(max)) ----------
__global__ __launch_bounds__(512) void cafc(const float* __restrict__ cs,
    const float* __restrict__ cm, const float* __restrict__ w1,
    const float* __restrict__ w2, float* __restrict__ ac) {
  __shared__ float sa[512], sx[512], hsum[8][4];
  int tid = threadIdx.x;
  sa[tid] = (cs[tid] + cs[512 + tid]) * (1.f / HT);
  sx[tid] = fmaxf(cm[tid], cm[512 + tid]);
  __syncthreads();
  if (tid < 32) {
    int b = tid >> 2, m = tid & 3;
    float s1 = 0.f, s2 = 0.f;
    #pragma unroll
    for (int cc = 0; cc < 64; ++cc) {
      float wv = w1[m * 64 + cc];
      s1 += sa[b * 64 + cc] * wv;
      s2 += sx[b * 64 + cc] * wv;
    }
    hsum[b][m] = fmaxf(s1, 0.f) + fmaxf(s2, 0.f);
  }
  __syncthreads();
  int b = tid >> 6, cc = tid & 63;
  float f = 0.f;
  #pragma unroll
  for (int m = 0; m < 4; ++m) f += hsum[b][m] * w2[cc * 4 + m];
  ac[tid] = sigmoidf_(f);
}

// ---------- 7x7 conv over 2 channels + sigmoid (LDS row-pair tile) ----------
__global__ __launch_bounds__(256) void conv7(const float* __restrict__ comb,
    const float* __restrict__ w, float* __restrict__ as_) {
  __shared__ float sm[2][8][408];
  __shared__ float sw[98];
  const int b = blockIdx.x / 31, hp = blockIdx.x % 31;
  const int h0 = hp * 2;
  const float* cb0 = comb + b * 2 * HT;
  const int tid = threadIdx.x;
  if (tid < 98) sw[tid] = w[tid];
  for (int e = tid; e < 2 * 8 * 408; e += 256) {
    int ci = e / 3264, rem = e - ci * 3264;
    int r = rem / 408, tt = rem - r * 408;
    int hh = h0 - 3 + r, t = tt - 4;
    float v = 0.f;
    if (hh >= 0 && hh < H_ && t >= 0 && t < T_) v = cb0[ci * HT + hh * T_ + t];
    sm[ci][r][tt] = v;
  }
  __syncthreads();
  for (int o = tid; o < 800; o += 256) {
    int oh = o / 400, ot = o - oh * 400;
    float acc = 0.f;
    #pragma unroll
    for (int ci = 0; ci < 2; ++ci)
      #pragma unroll
      for (int u = 0; u < 7; ++u)
        #pragma unroll
        for (int v = 0; v < 7; ++v)
          acc += sw[ci * 49 + u * 7 + v] * sm[ci][oh + u][ot + v + 1];
    as_[b * HT + (h0 + oh) * T_ + ot] = sigmoidf_(acc);
  }
}

// ---------- ssmctA: build P[i]=A^(2^i), q[i]=s_(2^i) tables (per half) ----------
__global__ __launch_bounds__(1024) void ssmctA(const float* __restrict__ A_,
    const float* __restrict__ Bv_, float* __restrict__ Pg, float* __restrict__ qg) {
  const int hf = blockIdx.x;
  const float* A = A_ + hf * 1024;
  const float* Bv = Bv_ + hf * 32;
  __shared__ float Pbuf[2][32 * 33];
  __shared__ float qbuf[2][32];
  const int tid = threadIdx.x;
  float* Pc = Pbuf[0]; float* Pn = Pbuf[1];
  float* qc = qbuf[0]; float* qn = qbuf[1];
  Pc[(tid >> 5) * 33 + (tid & 31)] = A[tid];
  if (tid < 32) qc[tid] = Bv[tid];
  __syncthreads();
  for (int i = 0; i < 9; ++i) {
    Pg[(hf * 9 + i) * 1024 + tid] = Pc[(tid >> 5) * 33 + (tid & 31)];
    if (tid < 32) qg[(hf * 9 + i) * 32 + tid] = qc[tid];
    if (i == 8) break;
    const int r = tid >> 5, cc = tid & 31;
    float s0 = 0.f, s1 = 0.f, s2 = 0.f, s3 = 0.f;
    #pragma unroll
    for (int k = 0; k < 32; k += 4) {
      s0 += Pc[r * 33 + k + 0] * Pc[(k + 0) * 33 + cc];
      s1 += Pc[r * 33 + k + 1] * Pc[(k + 1) * 33 + cc];
      s2 += Pc[r * 33 + k + 2] * Pc[(k + 2) * 33 + cc];
      s3 += Pc[r * 33 + k + 3] * Pc[(k + 3) * 33 + cc];
    }
    float qv = 0.f;
    if (tid < 32) {
      float a0 = 0.f, a1 = 0.f;
      #pragma unroll
      for (int k = 0; k < 32; k += 2) {
        a0 += Pc[tid * 33 + k] * qc[k];
        a1 += Pc[tid * 33 + k + 1] * qc[k + 1];
      }
      qv = qc[tid] + a0 + a1;
    }
    Pn[r * 33 + cc] = s0 + s1 + s2 + s3;
    if (tid < 32) qn[tid] = qv;
    __syncthreads();
    float* tp = Pc; Pc = Pn; Pn = tp;
    float* tq = qc; qc = qn; qn = tq;
  }
}

// ---------- ssmctB: per-t bit-walk (32 lanes hold the state), ct = s@Cm ----------
__global__ __launch_bounds__(1024) void ssmctB(const float* __restrict__ Pg,
    const float* __restrict__ qg, const float* __restrict__ Cm_,
    float* __restrict__ ct) {
  const int hf = blockIdx.y;
  __shared__ float P[9][32][33];
  __shared__ float q[9][32];
  __shared__ float Cs[32 * 64];
  __shared__ float st[32][33];
  const int tid = threadIdx.x;
  #pragma unroll
  for (int i = 0; i < 9; ++i) {
    int rem = tid;
    P[i][rem >> 5][rem & 31] = Pg[(hf * 9 + i) * 1024 + rem];
  }
  if (tid < 9 * 32) q[tid >> 5][tid & 31] = qg[hf * 9 * 32 + tid];
  for (int e = tid; e < 2048; e += 1024) Cs[e] = Cm_[hf * 2048 + e];
  __syncthreads();
  const int grp = tid >> 5, j = tid & 31;
  const int tIdx = blockIdx.x * 32 + grp;
  const int n = tIdx + 1;
  float s = 0.f;
  #pragma unroll
  for (int i = 0; i < 9; ++i) {
    st[grp][j] = s;                        // in-wave exchange (no barrier)
    float a0 = q[i][j], a1 = 0.f;
    #pragma unroll
    for (int k = 0; k < 32; k += 2) {
      a0 += P[i][j][k] * st[grp][k];
      a1 += P[i][j][k + 1] * st[grp][k + 1];
    }
    s = ((n >> i) & 1) ? (a0 + a1) : s;
  }
  st[grp][j] = s;
  __syncthreads();
  #pragma unroll
  for (int e0 = 0; e0 < 2048; e0 += 1024) {
    int e = e0 + tid;
    int ts = e >> 6, c = e & 63;
    float a0 = 0.f, a1 = 0.f;
    #pragma unroll
    for (int k = 0; k < 32; k += 2) {
      a0 += st[ts][k] * Cs[k * 64 + c];
      a1 += st[ts][k + 1] * Cs[(k + 1) * 64 + c];
    }
    int tg = blockIdx.x * 32 + ts;
    if (tg < T_) ct[(hf * T_ + tg) * C_ + c] = a0 + a1;
  }
}

// ---------- fused SSM + residual + LayerNorm + spatial gate: bf16 in ----------
template<bool OUTF32>
__global__ __launch_bounds__(256) void k8(const bh* __restrict__ cb,
    const bh* __restrict__ b2, const float* __restrict__ as_,
    const float* __restrict__ ct, const float* __restrict__ D,
    const float* __restrict__ lng, const float* __restrict__ lnb,
    void* __restrict__ out, int rev) {
  __shared__ float ct_s[64 * 65];
  __shared__ float red[4 * 2 * 66];
  const int tid = threadIdx.x;
  const int pl = tid & 63, wg = tid >> 6;
  const int p0 = blockIdx.x * 64;
  #pragma unroll
  for (int k = 0; k < 16; ++k) {
    int idx = k * 256 + tid;
    int r = idx >> 6, c2 = idx & 63;
    int t = (p0 + r) % T_;
    ct_s[r * 65 + c2] = ct[t * C_ + c2];
  }
  const int p = p0 + pl;
  const int b = p / HT, ht = p - b * HT;
  const int h = ht / T_, t = ht - h * T_;
  __syncthreads();
  const bh* cbp = cb + b * CHT + ht;
  const bh* b2p = b2 + b * CHT + ht;
  float o[16];
  float sum = 0.f;
  #pragma unroll
  for (int i = 0; i < 16; ++i) {
    int c = wg * 16 + i;
    float xv = b2f(cbp[c * HT]);
    int c2 = (62 * c + h) & 63;          // reshape(b*h, c, t) scrambling
    float u = ct_s[pl * 65 + c2] + xv * D[c2];
    float v = xv + gelu_(u);
    o[i] = v; sum += v;
  }
  red[wg * 132 + pl] = sum;
  __syncthreads();
  float S = red[0 * 132 + pl] + red[1 * 132 + pl] + red[2 * 132 + pl] + red[3 * 132 + pl];
  float mu = S * (1.f / 64.f);
  float vp = 0.f;
  #pragma unroll
  for (int i = 0; i < 16; ++i) { float d = o[i] - mu; vp += d * d; }
  red[wg * 132 + 66 + pl] = vp;
  __syncthreads();
  float Q = red[0 * 132 + 66 + pl] + red[1 * 132 + 66 + pl] +
            red[2 * 132 + 66 + pl] + red[3 * 132 + 66 + pl];
  float rstd = rsqrtf(Q * (1.f / 64.f) + 1e-5f);
  float av = as_[p];
  int htw = rev ? (h * T_ + (T_ - 1 - t)) : ht;
  #pragma unroll
  for (int i = 0; i < 16; ++i) {
    int c = wg * 16 + i;
    float y = (o[i] - mu) * rstd * lng[c] + lnb[c];
    float bv = b2f(b2p[c * HT]);
    float r = y * sigmoidf_(bv * bv * av);
    if constexpr (OUTF32) ((float*)out)[b * CHT + htw + c * HT] = r;
    else                  ((bh*)out)[b * CHT + htw + c * HT] = f2b(r);
  }
}

extern "C" void kernel_launch(void* const* d_in, const int* in_sizes, int n_in,
                              void* d_out, int out_size, void* d_ws, size_t ws_size,
                              hipStream_t stream) {
  const float* x    = (const float*)d_in[0];
  const float* in_w = (const float*)d_in[1];
  const float* dwdw = (const float*)d_in[2];
  const float* dwpw = (const float*)d_in[3];
  const float* dwg  = (const float*)d_in[4];
  const float* dwb  = (const float*)d_in[5];
  const float* caw1 = (const float*)d_in[6];
  const float* caw2 = (const float*)d_in[7];
  const float* saw  = (const float*)d_in[8];
  const float* d1dw = (const float*)d_in[9];
  const float* d1pw = (const float*)d_in[10];
  const float* d1g  = (const float*)d_in[11];
  const float* d1b  = (const float*)d_in[12];
  const float* ssmA = (const float*)d_in[13];
  const float* ssmBv= (const float*)d_in[14];
  const float* ssmC = (const float*)d_in[15];
  const float* ssmD = (const float*)d_in[16];
  const float* lng  = (const float*)d_in[17];
  const float* lnb  = (const float*)d_in[18];
  const float* outw = (const float*)d_in[19];
  const float* outg = (const float*)d_in[20];
  const float* outb = (const float*)d_in[21];

  size_t need = (size_t)3 * NTOT * 4
              + (size_t)(2 * NPOS + NPOS + 1024 + 1024 + 512
                         + 2 * T_ * C_ + 2 * 9 * 1024 + 2 * 9 * 32) * 4
              + (size_t)8 * 4096 * 2;
  if (ws_size < need) return;

  // R0: X (f32) / X_out; R1: {d0,d1} then cb (bh halves); R2: {b1,b2} (bh halves)
  float* R0f = (float*)d_ws;
  float* R1f = R0f + NTOT;
  float* R2f = R1f + NTOT;
  bh* R0b  = (bh*)R0f;
  bh* R1lo = (bh*)R1f; bh* R1hi = R1lo + NTOT;
  bh* R2lo = (bh*)R2f; bh* R2hi = R2lo + NTOT;
  float* fbase = R2f + NTOT;
  float* comb  = fbase;            // B*2*HT
  float* as_   = comb + 2 * NPOS;  // B*HT
  float* casum = as_ + NPOS;       // 1024
  float* camax = casum + 1024;     // 1024
  float* ac    = camax + 1024;     // 512
  float* ct    = ac + 512;         // 2*T*C
  float* Pg    = ct + 2 * T_ * C_; // 2*9*1024
  float* qg    = Pg + 2 * 9 * 1024;// 2*9*32
  bh* Wbf = (bh*)(qg + 2 * 9 * 32);// 8 slots * 4096 bf16

  prep<<<16, 256, 0, stream>>>(in_w, dwpw, dwg, d1pw, d1g, outw, outg, Wbf);
  ssmctA<<<2, 1024, 0, stream>>>(ssmA, ssmBv, Pg, qg);
  ssmctB<<<dim3(13, 2), 1024, 0, stream>>>(Pg, qg, ssmC, ct);
  // input proj: f32 in -> f32 out (X role -> R0)
  pwk<0, false, false, false, true, true><<<1550, 256, 0, stream>>>(
      x, Wbf + 0 * 4096, nullptr, nullptr, nullptr, R0f, nullptr);

  auto run_half = [&](int hf) {
    const float* dw0 = dwdw + (hf * 2 + 0) * C_ * 25;
    const float* dw1 = dwdw + (hf * 2 + 1) * C_ * 25;
    const float* b0  = dwb + (hf * 2 + 0) * C_;
    const float* b1w = dwb + (hf * 2 + 1) * C_;
    // X (f32, R0) -> d0 (R1lo), d1 (R1hi)
    dw5dual<<<dim3(7, 512), 256, 0, stream>>>(R0f, dw0, dw1, R1lo, R1hi);
    // merged: b1 = relu(bn(pw(d0))) -> R2lo;  b2 = relu(bn(pw(d1))) -> R2hi + comb
    pwk_bb<<<3100, 256, 0, stream>>>(R1lo, R1hi,
                                     Wbf + (1 + hf * 3) * 4096,
                                     Wbf + (2 + hf * 3) * 4096,
                                     dwb + (hf * 2 + 0) * C_,
                                     dwb + (hf * 2 + 1) * C_,
                                     R2lo, R2hi, comb);
    (void)b0; (void)b1w;
    chanred<<<1024, 256, 0, stream>>>(R2lo, casum, camax);
    cafc<<<1, 512, 0, stream>>>(casum, camax, caw1 + hf * 4 * 64, caw2 + hf * 64 * 4, ac);
    conv7<<<248, 256, 0, stream>>>(comb, saw + hf * 98, as_);
    // cb = sigmoid(bn(pw(dw1x3(b1^2*ac)))) -> R1lo (d0 dead)
    pwk<2, false, false, true, false, false><<<1550, 256, 0, stream>>>(
        R2lo, Wbf + (3 + hf * 3) * 4096, d1b + hf * C_, ac, d1dw + hf * C_ * 3,
        R1lo, nullptr);
    // k8: cb (R1lo), b2 (R2hi) -> X_out in R0 (X dead)
    if (hf == 0)
      k8<true><<<3100, 256, 0, stream>>>(R1lo, R2hi, as_, ct + hf * T_ * C_,
                                         ssmD + hf * C_, lng + hf * C_,
                                         lnb + hf * C_, R0f, 1);
    else
      k8<false><<<3100, 256, 0, stream>>>(R1lo, R2hi, as_, ct + hf * T_ * C_,
                                          ssmD + hf * C_, lng + hf * C_,
                                          lnb + hf * C_, R0b, 0);
  };

  run_half(0);   // X_out reversed f32 -> R0 (= input of half 1)
  run_half(1);   // X_out (reversed domain) bf16 -> R0
  // final pw: bf16 in (REV undo) -> f32 out + bn + relu
  pwk<1, true, false, false, false, true><<<1550, 256, 0, stream>>>(
      R0b, Wbf + 7 * 4096, outb, nullptr, nullptr, (float*)d_out, nullptr);
}